// Round 1
// baseline (630.169 us; speedup 1.0000x reference)
//
#include <hip/hip_runtime.h>
#include <stdint.h>

// ---------------------------------------------------------------------------
// GCN 3-layer forward on MI355X.
// Strategy: build CSR (by dst) once per launch, then per layer:
//   GEMM (LDS-staged W, f32 VALU)  ->  gather-based aggregation (no float
//   atomics; one wave per node, coalesced row gathers) with fused bias+ReLU.
// ---------------------------------------------------------------------------

__device__ __forceinline__ float4 fma4(float a, float4 b, float4 c) {
  return make_float4(fmaf(a, b.x, c.x), fmaf(a, b.y, c.y),
                     fmaf(a, b.z, c.z), fmaf(a, b.w, c.w));
}

__global__ void zero_cnt_kernel(int* cnt, int n) {
  int i = blockIdx.x * blockDim.x + threadIdx.x;
  if (i < n) cnt[i] = 0;
}

__global__ void hist_kernel(const int* __restrict__ dst, int E,
                            int* __restrict__ cnt) {
  int stride = gridDim.x * blockDim.x;
  for (int e = blockIdx.x * blockDim.x + threadIdx.x; e < E; e += stride)
    atomicAdd(&cnt[dst[e]], 1);
}

__global__ void dinv_kernel(const int* __restrict__ cnt,
                            float* __restrict__ dinv, int N) {
  int i = blockIdx.x * blockDim.x + threadIdx.x;
  if (i < N) dinv[i] = rsqrtf((float)(cnt[i] + 1));  // +1 self-loop; deg>=1
}

// ---- 3-phase exclusive scan over cnt[N] (N <= 131072: NB <= 512) ----------
__global__ void scan_blocksum(const int* __restrict__ cnt, int N,
                              int* __restrict__ bsum) {
  __shared__ int s[256];
  int i = blockIdx.x * 256 + threadIdx.x;
  s[threadIdx.x] = (i < N) ? cnt[i] : 0;
  __syncthreads();
  for (int off = 128; off > 0; off >>= 1) {
    if (threadIdx.x < off) s[threadIdx.x] += s[threadIdx.x + off];
    __syncthreads();
  }
  if (threadIdx.x == 0) bsum[blockIdx.x] = s[0];
}

__global__ void scan_bsums(int* bsum, int NB) {
  __shared__ int s[512];
  int t = threadIdx.x;
  int v = (t < NB) ? bsum[t] : 0;
  s[t] = v;
  __syncthreads();
  for (int off = 1; off < 512; off <<= 1) {
    int u = (t >= off) ? s[t - off] : 0;
    __syncthreads();
    s[t] += u;
    __syncthreads();
  }
  if (t < NB) bsum[t] = s[t] - v;  // exclusive block base
}

__global__ void scan_final(const int* __restrict__ cnt, int N,
                           const int* __restrict__ bsum,
                           int* __restrict__ offsets, int* __restrict__ cursor) {
  __shared__ int s[256];
  int t = threadIdx.x;
  int i = blockIdx.x * 256 + t;
  int v = (i < N) ? cnt[i] : 0;
  s[t] = v;
  __syncthreads();
  for (int off = 1; off < 256; off <<= 1) {
    int u = (t >= off) ? s[t - off] : 0;
    __syncthreads();
    s[t] += u;
    __syncthreads();
  }
  int excl = bsum[blockIdx.x] + s[t] - v;
  if (i < N) { offsets[i] = excl; cursor[i] = excl; }
  if (i == N - 1) offsets[N] = excl + v;  // == E
}

__global__ void build_kernel(const int* __restrict__ ei, int E,
                             const float* __restrict__ dinv,
                             int* __restrict__ cursor,
                             int2* __restrict__ edata) {
  int stride = gridDim.x * blockDim.x;
  for (int e = blockIdx.x * blockDim.x + threadIdx.x; e < E; e += stride) {
    int s = ei[e];         // src
    int d = ei[E + e];     // dst
    int pos = atomicAdd(&cursor[d], 1);
    edata[pos] = make_int2(s, __float_as_int(dinv[s]));
  }
}

// ---- GEMM: H[N,D] = X[N,K] @ W[K,D]; W staged in LDS (32 KB) --------------
template <int K, int D>
__global__ __launch_bounds__(256) void gemm_kernel(const float* __restrict__ X,
                                                   const float* __restrict__ W,
                                                   float* __restrict__ H, int N) {
  constexpr int CG = D / 4;        // col groups of 4
  constexpr int TY = 256 / CG;     // row-threads per block
  constexpr int ROWS = TY * 4;     // rows per block
  __shared__ float Ws[K * D];
  for (int i = threadIdx.x; i < K * D / 4; i += 256)
    reinterpret_cast<float4*>(Ws)[i] = reinterpret_cast<const float4*>(W)[i];
  __syncthreads();

  const int tx = threadIdx.x % CG;
  const int ty = threadIdx.x / CG;
  const int rbase = blockIdx.x * ROWS + ty;

  float4 acc[4];
  int r[4];
#pragma unroll
  for (int i = 0; i < 4; i++) {
    acc[i] = make_float4(0.f, 0.f, 0.f, 0.f);
    int rr = rbase + i * TY;
    r[i] = (rr < N) ? rr : (N - 1);  // clamp: redundant read, store is guarded
  }

  for (int k = 0; k < K; k += 4) {
    float4 wv0 = *reinterpret_cast<const float4*>(&Ws[(k + 0) * D + tx * 4]);
    float4 wv1 = *reinterpret_cast<const float4*>(&Ws[(k + 1) * D + tx * 4]);
    float4 wv2 = *reinterpret_cast<const float4*>(&Ws[(k + 2) * D + tx * 4]);
    float4 wv3 = *reinterpret_cast<const float4*>(&Ws[(k + 3) * D + tx * 4]);
#pragma unroll
    for (int i = 0; i < 4; i++) {
      float4 xv = *reinterpret_cast<const float4*>(&X[(size_t)r[i] * K + k]);
      acc[i] = fma4(xv.x, wv0, acc[i]);
      acc[i] = fma4(xv.y, wv1, acc[i]);
      acc[i] = fma4(xv.z, wv2, acc[i]);
      acc[i] = fma4(xv.w, wv3, acc[i]);
    }
  }

#pragma unroll
  for (int i = 0; i < 4; i++) {
    int rr = rbase + i * TY;
    if (rr < N)
      *reinterpret_cast<float4*>(&H[(size_t)rr * D + tx * 4]) = acc[i];
  }
}

// ---- Aggregation: one 64-lane wave per node; lane d owns feature(s) d -----
// out[n] = relu?( dinv[n]^2 * h[n] + sum_e dinv[src]*dinv[n]*h[src] + bias )
template <int VEC, bool RELU>
__global__ __launch_bounds__(256) void agg_kernel(
    const float* __restrict__ h, const int2* __restrict__ edata,
    const int* __restrict__ offsets, const float* __restrict__ dinv,
    const float* __restrict__ bias, float* __restrict__ out, int N) {
  constexpr int D = 64 * VEC;
  int node = blockIdx.x * (blockDim.x >> 6) + (threadIdx.x >> 6);
  if (node >= N) return;
  int lane = threadIdx.x & 63;

  float dn = dinv[node];
  float acc0, acc1 = 0.f;
  if constexpr (VEC == 1) {
    acc0 = h[(size_t)node * D + lane] * dn * dn;
  } else {
    float2 hv = *reinterpret_cast<const float2*>(&h[(size_t)node * D + lane * 2]);
    acc0 = hv.x * dn * dn;
    acc1 = hv.y * dn * dn;
  }

  int e = offsets[node];
  const int e1 = offsets[node + 1];

  for (; e + 4 <= e1; e += 4) {
    int2 d0 = edata[e + 0];
    int2 d1 = edata[e + 1];
    int2 d2 = edata[e + 2];
    int2 d3 = edata[e + 3];
    float w0 = __int_as_float(d0.y) * dn;
    float w1 = __int_as_float(d1.y) * dn;
    float w2 = __int_as_float(d2.y) * dn;
    float w3 = __int_as_float(d3.y) * dn;
    if constexpr (VEC == 1) {
      float g0 = h[(size_t)d0.x * D + lane];
      float g1 = h[(size_t)d1.x * D + lane];
      float g2 = h[(size_t)d2.x * D + lane];
      float g3 = h[(size_t)d3.x * D + lane];
      acc0 = fmaf(g0, w0, acc0);
      acc0 = fmaf(g1, w1, acc0);
      acc0 = fmaf(g2, w2, acc0);
      acc0 = fmaf(g3, w3, acc0);
    } else {
      float2 g0 = *reinterpret_cast<const float2*>(&h[(size_t)d0.x * D + lane * 2]);
      float2 g1 = *reinterpret_cast<const float2*>(&h[(size_t)d1.x * D + lane * 2]);
      float2 g2 = *reinterpret_cast<const float2*>(&h[(size_t)d2.x * D + lane * 2]);
      float2 g3 = *reinterpret_cast<const float2*>(&h[(size_t)d3.x * D + lane * 2]);
      acc0 = fmaf(g0.x, w0, acc0); acc1 = fmaf(g0.y, w0, acc1);
      acc0 = fmaf(g1.x, w1, acc0); acc1 = fmaf(g1.y, w1, acc1);
      acc0 = fmaf(g2.x, w2, acc0); acc1 = fmaf(g2.y, w2, acc1);
      acc0 = fmaf(g3.x, w3, acc0); acc1 = fmaf(g3.y, w3, acc1);
    }
  }
  for (; e < e1; ++e) {
    int2 dd = edata[e];
    float wg = __int_as_float(dd.y) * dn;
    if constexpr (VEC == 1) {
      acc0 = fmaf(h[(size_t)dd.x * D + lane], wg, acc0);
    } else {
      float2 g = *reinterpret_cast<const float2*>(&h[(size_t)dd.x * D + lane * 2]);
      acc0 = fmaf(g.x, wg, acc0);
      acc1 = fmaf(g.y, wg, acc1);
    }
  }

  if constexpr (VEC == 1) {
    float v0 = acc0 + bias[lane];
    if (RELU) v0 = fmaxf(v0, 0.f);
    out[(size_t)node * D + lane] = v0;
  } else {
    float v0 = acc0 + bias[lane * 2 + 0];
    float v1 = acc1 + bias[lane * 2 + 1];
    if (RELU) { v0 = fmaxf(v0, 0.f); v1 = fmaxf(v1, 0.f); }
    *reinterpret_cast<float2*>(&out[(size_t)node * D + lane * 2]) =
        make_float2(v0, v1);
  }
}

extern "C" void kernel_launch(void* const* d_in, const int* in_sizes, int n_in,
                              void* d_out, int out_size, void* d_ws,
                              size_t ws_size, hipStream_t stream) {
  const float* x  = (const float*)d_in[0];
  const int*   ei = (const int*)d_in[1];
  const float* W1 = (const float*)d_in[2];
  const float* b1 = (const float*)d_in[3];
  const float* W2 = (const float*)d_in[4];
  const float* b2 = (const float*)d_in[5];
  const float* W3 = (const float*)d_in[6];
  const float* b3 = (const float*)d_in[7];

  const int N = in_sizes[0] / 128;
  const int E = in_sizes[1] / 2;

  // Workspace carve-out (~117 MB for N=100K, E=1.6M)
  char* w = (char*)d_ws;
  int* cnt = (int*)w;        w += (size_t)N * 4;
  int* offsets = (int*)w;    w += (size_t)(N + 2) * 4;  // +pad keeps 8B align
  int* cursor = (int*)w;     w += (size_t)N * 4;
  float* dinv = (float*)w;   w += (size_t)N * 4;
  int2* edata = (int2*)w;    w += (size_t)E * 8;
  int* bsum = (int*)w;       w += 512 * 4;
  w = (char*)(((uintptr_t)w + 255) & ~(uintptr_t)255);
  float* bufA = (float*)w;   w += (size_t)N * 128 * 4;
  float* bufB = (float*)w;   /* w += (size_t)N * 128 * 4; */

  const int NB = (N + 255) / 256;  // 391 for N=100000 (<=512 required)

  // ---- CSR build (reused by all 3 layers) ----
  zero_cnt_kernel<<<NB, 256, 0, stream>>>(cnt, N);
  hist_kernel<<<2048, 256, 0, stream>>>(ei + E, E, cnt);
  dinv_kernel<<<NB, 256, 0, stream>>>(cnt, dinv, N);
  scan_blocksum<<<NB, 256, 0, stream>>>(cnt, N, bsum);
  scan_bsums<<<1, 512, 0, stream>>>(bsum, NB);
  scan_final<<<NB, 256, 0, stream>>>(cnt, N, bsum, offsets, cursor);
  build_kernel<<<2048, 256, 0, stream>>>(ei, E, dinv, cursor, edata);

  // ---- Layer 1: x[N,128]@W1[128,64] -> agg(+b1, relu) ----
  gemm_kernel<128, 64><<<(N + 63) / 64, 256, 0, stream>>>(x, W1, bufA, N);
  agg_kernel<1, true><<<(N + 3) / 4, 256, 0, stream>>>(bufA, edata, offsets,
                                                       dinv, b1, bufB, N);
  // ---- Layer 2: [N,64]@W2[64,128] -> agg(+b2, relu) ----
  gemm_kernel<64, 128><<<(N + 31) / 32, 256, 0, stream>>>(bufB, W2, bufA, N);
  agg_kernel<2, true><<<(N + 3) / 4, 256, 0, stream>>>(bufA, edata, offsets,
                                                       dinv, b2, bufB, N);
  // ---- Layer 3: [N,128]@W3[128,64] -> agg(+b3) -> d_out ----
  gemm_kernel<128, 64><<<(N + 63) / 64, 256, 0, stream>>>(bufB, W3, bufA, N);
  agg_kernel<1, false><<<(N + 3) / 4, 256, 0, stream>>>(bufA, edata, offsets,
                                                        dinv, b3, (float*)d_out, N);
}

// Round 2
// 523.455 us; speedup vs baseline: 1.2039x; 1.2039x over previous
//
#include <hip/hip_runtime.h>
#include <stdint.h>

// ---------------------------------------------------------------------------
// GCN 3-layer forward on MI355X.
// Build exact CSR-by-dst via 3-phase bucket sort (no scattered-line writes):
//   A1: per-wg LDS histogram over coarse buckets (dst>>8) -> M[bucket][wg]
//   scan(M)
//   A2: per-wg scatter into reserved contiguous runs  (edata1: src,dst)
//   B : per-bucket exact LDS counting sort -> offsets, dinv, edata2 (src only)
// Per layer: GEMM (LDS-staged W, f32 VALU) -> gather aggregation (one wave
// per node, zero float atomics) with fused bias+ReLU.
// ---------------------------------------------------------------------------

#define NWGA 256  // workgroups for edge-chunk passes (scan limit: NBUK*NWGA/256 <= 512)

__device__ __forceinline__ float4 fma4(float a, float4 b, float4 c) {
  return make_float4(fmaf(a, b.x, c.x), fmaf(a, b.y, c.y),
                     fmaf(a, b.z, c.z), fmaf(a, b.w, c.w));
}

// ---- A1: per-wg bucket histogram ------------------------------------------
__global__ __launch_bounds__(256) void bucket_hist_kernel(
    const int* __restrict__ dst, int E, int chunk, int NBUK,
    int* __restrict__ M /* [NBUK][NWGA] */) {
  __shared__ int hist[512];
  const int w = blockIdx.x, t = threadIdx.x;
  for (int i = t; i < NBUK; i += 256) hist[i] = 0;
  __syncthreads();
  const int e0 = w * chunk;
  const int e1 = min(e0 + chunk, E);
  for (int e = e0 + t; e < e1; e += 256) atomicAdd(&hist[dst[e] >> 8], 1);
  __syncthreads();
  for (int i = t; i < NBUK; i += 256) M[i * NWGA + w] = hist[i];
}

// ---- scan helpers (block reduce + single-block scan + in-place final) -----
__global__ void scan_blocksum(const int* __restrict__ data, int len,
                              int* __restrict__ bsum) {
  __shared__ int s[256];
  int i = blockIdx.x * 256 + threadIdx.x;
  s[threadIdx.x] = (i < len) ? data[i] : 0;
  __syncthreads();
  for (int off = 128; off > 0; off >>= 1) {
    if (threadIdx.x < off) s[threadIdx.x] += s[threadIdx.x + off];
    __syncthreads();
  }
  if (threadIdx.x == 0) bsum[blockIdx.x] = s[0];
}

__global__ void scan_bsums(int* bsum, int NB) {
  __shared__ int s[512];
  int t = threadIdx.x;
  int v = (t < NB) ? bsum[t] : 0;
  s[t] = v;
  __syncthreads();
  for (int off = 1; off < 512; off <<= 1) {
    int u = (t >= off) ? s[t - off] : 0;
    __syncthreads();
    s[t] += u;
    __syncthreads();
  }
  if (t < NB) bsum[t] = s[t] - v;  // exclusive block base
}

__global__ void scan_final(int* __restrict__ data, int len,
                           const int* __restrict__ bsum) {
  __shared__ int s[256];
  int t = threadIdx.x;
  int i = blockIdx.x * 256 + t;
  int v = (i < len) ? data[i] : 0;
  s[t] = v;
  __syncthreads();
  for (int off = 1; off < 256; off <<= 1) {
    int u = (t >= off) ? s[t - off] : 0;
    __syncthreads();
    s[t] += u;
    __syncthreads();
  }
  if (i < len) data[i] = bsum[blockIdx.x] + s[t] - v;  // exclusive, in-place
}

// ---- A2: scatter edges into reserved contiguous bucket runs ---------------
__global__ __launch_bounds__(256) void bucket_scatter_kernel(
    const int* __restrict__ ei, int E, int chunk, int NBUK,
    const int* __restrict__ Mscan, int2* __restrict__ edata1) {
  __shared__ int cur[512];
  const int w = blockIdx.x, t = threadIdx.x;
  for (int i = t; i < NBUK; i += 256) cur[i] = Mscan[i * NWGA + w];
  __syncthreads();
  const int e0 = w * chunk;
  const int e1 = min(e0 + chunk, E);
  for (int e = e0 + t; e < e1; e += 256) {
    int s = ei[e];
    int d = ei[E + e];
    int pos = atomicAdd(&cur[d >> 8], 1);
    edata1[pos] = make_int2(s, d);
  }
}

// ---- B: per-bucket exact counting sort -> CSR offsets, dinv, src list -----
__global__ __launch_bounds__(256) void bucket_sort_kernel(
    const int2* __restrict__ edata1, const int* __restrict__ Mscan, int E,
    int N, int NBUK, int* __restrict__ offsets, float* __restrict__ dinv,
    int* __restrict__ edata2) {
  __shared__ int hist[256];
  __shared__ int cursor[256];
  const int b = blockIdx.x, t = threadIdx.x;
  const int base = Mscan[b * NWGA];
  const int end = (b + 1 < NBUK) ? Mscan[(b + 1) * NWGA] : E;
  const int nodebase = b << 8;
  hist[t] = 0;
  __syncthreads();
  for (int e = base + t; e < end; e += 256)
    atomicAdd(&hist[edata1[e].y - nodebase], 1);
  __syncthreads();
  const int deg = hist[t];
  for (int off = 1; off < 256; off <<= 1) {  // inclusive scan
    int u = (t >= off) ? hist[t - off] : 0;
    __syncthreads();
    hist[t] += u;
    __syncthreads();
  }
  const int excl = hist[t] - deg;
  const int node = nodebase + t;
  cursor[t] = base + excl;
  if (node < N) {
    offsets[node] = base + excl;
    dinv[node] = rsqrtf((float)(deg + 1));  // +1 self-loop
  }
  if (node == N - 1) offsets[N] = E;
  __syncthreads();
  for (int e = base + t; e < end; e += 256) {
    int2 sd = edata1[e];
    int pos = atomicAdd(&cursor[sd.y - nodebase], 1);
    edata2[pos] = sd.x;
  }
}

// ---- GEMM: H[N,D] = X[N,K] @ W[K,D]; W staged in LDS ----------------------
template <int K, int D>
__global__ __launch_bounds__(256) void gemm_kernel(const float* __restrict__ X,
                                                   const float* __restrict__ W,
                                                   float* __restrict__ H, int N) {
  constexpr int CG = D / 4;
  constexpr int TY = 256 / CG;
  constexpr int ROWS = TY * 4;
  __shared__ float Ws[K * D];
  for (int i = threadIdx.x; i < K * D / 4; i += 256)
    reinterpret_cast<float4*>(Ws)[i] = reinterpret_cast<const float4*>(W)[i];
  __syncthreads();

  const int tx = threadIdx.x % CG;
  const int ty = threadIdx.x / CG;
  const int rbase = blockIdx.x * ROWS + ty;

  float4 acc[4];
  int r[4];
#pragma unroll
  for (int i = 0; i < 4; i++) {
    acc[i] = make_float4(0.f, 0.f, 0.f, 0.f);
    int rr = rbase + i * TY;
    r[i] = (rr < N) ? rr : (N - 1);
  }

  for (int k = 0; k < K; k += 4) {
    float4 wv0 = *reinterpret_cast<const float4*>(&Ws[(k + 0) * D + tx * 4]);
    float4 wv1 = *reinterpret_cast<const float4*>(&Ws[(k + 1) * D + tx * 4]);
    float4 wv2 = *reinterpret_cast<const float4*>(&Ws[(k + 2) * D + tx * 4]);
    float4 wv3 = *reinterpret_cast<const float4*>(&Ws[(k + 3) * D + tx * 4]);
#pragma unroll
    for (int i = 0; i < 4; i++) {
      float4 xv = *reinterpret_cast<const float4*>(&X[(size_t)r[i] * K + k]);
      acc[i] = fma4(xv.x, wv0, acc[i]);
      acc[i] = fma4(xv.y, wv1, acc[i]);
      acc[i] = fma4(xv.z, wv2, acc[i]);
      acc[i] = fma4(xv.w, wv3, acc[i]);
    }
  }

#pragma unroll
  for (int i = 0; i < 4; i++) {
    int rr = rbase + i * TY;
    if (rr < N)
      *reinterpret_cast<float4*>(&H[(size_t)rr * D + tx * 4]) = acc[i];
  }
}

// ---- Aggregation: one 64-lane wave per node -------------------------------
// out[n] = relu?( dinv[n]^2*h[n] + sum_e dinv[src]*dinv[n]*h[src] + bias )
template <int VEC, bool RELU>
__global__ __launch_bounds__(256) void agg_kernel(
    const float* __restrict__ h, const int* __restrict__ edata,
    const int* __restrict__ offsets, const float* __restrict__ dinv,
    const float* __restrict__ bias, float* __restrict__ out, int N) {
  constexpr int D = 64 * VEC;
  int node = blockIdx.x * (blockDim.x >> 6) + (threadIdx.x >> 6);
  if (node >= N) return;
  int lane = threadIdx.x & 63;

  float dn = dinv[node];
  float acc0, acc1 = 0.f;
  if constexpr (VEC == 1) {
    acc0 = h[(size_t)node * D + lane] * dn * dn;
  } else {
    float2 hv = *reinterpret_cast<const float2*>(&h[(size_t)node * D + lane * 2]);
    acc0 = hv.x * dn * dn;
    acc1 = hv.y * dn * dn;
  }

  int e = offsets[node];
  const int e1 = offsets[node + 1];

  for (; e + 4 <= e1; e += 4) {
    int s0 = edata[e + 0];
    int s1 = edata[e + 1];
    int s2 = edata[e + 2];
    int s3 = edata[e + 3];
    float w0 = dinv[s0] * dn;
    float w1 = dinv[s1] * dn;
    float w2 = dinv[s2] * dn;
    float w3 = dinv[s3] * dn;
    if constexpr (VEC == 1) {
      float g0 = h[(size_t)s0 * D + lane];
      float g1 = h[(size_t)s1 * D + lane];
      float g2 = h[(size_t)s2 * D + lane];
      float g3 = h[(size_t)s3 * D + lane];
      acc0 = fmaf(g0, w0, acc0);
      acc0 = fmaf(g1, w1, acc0);
      acc0 = fmaf(g2, w2, acc0);
      acc0 = fmaf(g3, w3, acc0);
    } else {
      float2 g0 = *reinterpret_cast<const float2*>(&h[(size_t)s0 * D + lane * 2]);
      float2 g1 = *reinterpret_cast<const float2*>(&h[(size_t)s1 * D + lane * 2]);
      float2 g2 = *reinterpret_cast<const float2*>(&h[(size_t)s2 * D + lane * 2]);
      float2 g3 = *reinterpret_cast<const float2*>(&h[(size_t)s3 * D + lane * 2]);
      acc0 = fmaf(g0.x, w0, acc0); acc1 = fmaf(g0.y, w0, acc1);
      acc0 = fmaf(g1.x, w1, acc0); acc1 = fmaf(g1.y, w1, acc1);
      acc0 = fmaf(g2.x, w2, acc0); acc1 = fmaf(g2.y, w2, acc1);
      acc0 = fmaf(g3.x, w3, acc0); acc1 = fmaf(g3.y, w3, acc1);
    }
  }
  for (; e < e1; ++e) {
    int s = edata[e];
    float wg = dinv[s] * dn;
    if constexpr (VEC == 1) {
      acc0 = fmaf(h[(size_t)s * D + lane], wg, acc0);
    } else {
      float2 g = *reinterpret_cast<const float2*>(&h[(size_t)s * D + lane * 2]);
      acc0 = fmaf(g.x, wg, acc0);
      acc1 = fmaf(g.y, wg, acc1);
    }
  }

  if constexpr (VEC == 1) {
    float v0 = acc0 + bias[lane];
    if (RELU) v0 = fmaxf(v0, 0.f);
    out[(size_t)node * D + lane] = v0;
  } else {
    float v0 = acc0 + bias[lane * 2 + 0];
    float v1 = acc1 + bias[lane * 2 + 1];
    if (RELU) { v0 = fmaxf(v0, 0.f); v1 = fmaxf(v1, 0.f); }
    *reinterpret_cast<float2*>(&out[(size_t)node * D + lane * 2]) =
        make_float2(v0, v1);
  }
}

extern "C" void kernel_launch(void* const* d_in, const int* in_sizes, int n_in,
                              void* d_out, int out_size, void* d_ws,
                              size_t ws_size, hipStream_t stream) {
  const float* x  = (const float*)d_in[0];
  const int*   ei = (const int*)d_in[1];
  const float* W1 = (const float*)d_in[2];
  const float* b1 = (const float*)d_in[3];
  const float* W2 = (const float*)d_in[4];
  const float* b2 = (const float*)d_in[5];
  const float* W3 = (const float*)d_in[6];
  const float* b3 = (const float*)d_in[7];

  const int N = in_sizes[0] / 128;
  const int E = in_sizes[1] / 2;
  const int NBUK = (N + 255) >> 8;          // 391 for N=100000 (<=512)
  const int MLEN = NBUK * NWGA;             // 100096
  const int chunk = (E + NWGA - 1) / NWGA;  // 6250

  // Workspace carve-out (~110 MB). edata1 aliases bufA (dead once B done).
  char* w = (char*)d_ws;
  int* M = (int*)w;          w += (size_t)MLEN * 4;
  int* bsum = (int*)w;       w += 512 * 4;
  int* offsets = (int*)w;    w += (size_t)(N + 2) * 4;
  float* dinv = (float*)w;   w += (size_t)N * 4;
  int* edata2 = (int*)w;     w += (size_t)E * 4;
  w = (char*)(((uintptr_t)w + 255) & ~(uintptr_t)255);
  float* bufA = (float*)w;   w += (size_t)N * 128 * 4;
  float* bufB = (float*)w;
  int2* edata1 = (int2*)bufA;  // alias: E*8 <= N*128*4

  const int NBS = (MLEN + 255) / 256;  // 391 scan blocks (<=512)

  // ---- CSR build ----
  bucket_hist_kernel<<<NWGA, 256, 0, stream>>>(ei + E, E, chunk, NBUK, M);
  scan_blocksum<<<NBS, 256, 0, stream>>>(M, MLEN, bsum);
  scan_bsums<<<1, 512, 0, stream>>>(bsum, NBS);
  scan_final<<<NBS, 256, 0, stream>>>(M, MLEN, bsum);
  bucket_scatter_kernel<<<NWGA, 256, 0, stream>>>(ei, E, chunk, NBUK, M, edata1);
  bucket_sort_kernel<<<NBUK, 256, 0, stream>>>(edata1, M, E, N, NBUK, offsets,
                                               dinv, edata2);

  // ---- Layer 1: x[N,128]@W1[128,64] -> agg(+b1, relu) ----
  gemm_kernel<128, 64><<<(N + 63) / 64, 256, 0, stream>>>(x, W1, bufA, N);
  agg_kernel<1, true><<<(N + 3) / 4, 256, 0, stream>>>(bufA, edata2, offsets,
                                                       dinv, b1, bufB, N);
  // ---- Layer 2: [N,64]@W2[64,128] -> agg(+b2, relu) ----
  gemm_kernel<64, 128><<<(N + 31) / 32, 256, 0, stream>>>(bufB, W2, bufA, N);
  agg_kernel<2, true><<<(N + 3) / 4, 256, 0, stream>>>(bufA, edata2, offsets,
                                                       dinv, b2, bufB, N);
  // ---- Layer 3: [N,128]@W3[128,64] -> agg(+b3) -> d_out ----
  gemm_kernel<128, 64><<<(N + 63) / 64, 256, 0, stream>>>(bufB, W3, bufA, N);
  agg_kernel<1, false><<<(N + 3) / 4, 256, 0, stream>>>(bufA, edata2, offsets,
                                                        dinv, b3, (float*)d_out, N);
}

// Round 3
// 460.197 us; speedup vs baseline: 1.3693x; 1.1375x over previous
//
#include <hip/hip_runtime.h>
#include <hip/hip_fp16.h>
#include <stdint.h>

// ---------------------------------------------------------------------------
// GCN 3-layer forward on MI355X.
// CSR build: 3-phase bucket sort (hist -> scan -> scatter -> per-bucket sort).
// Layers use A(XW) = (AX)W to keep ALL aggregations at D=64, and gather
// tables are fp16 (fp32 accumulate) to halve random-gather traffic:
//   t1 = x@W1 (fp16)          ; out1 = relu(Agg(t1)+b1)  (fp16)
//   a2 = Agg(out1) (fp32)     ; h2   = relu(a2@W2+b2)    (fp32)
//   t3 = h2@W3 (fp16)         ; out  = Agg(t3)+b3        (fp32)
// ---------------------------------------------------------------------------

#define NWGA 256  // workgroups for edge-chunk passes

struct __align__(8) Half4 { __half x, y, z, w; };

__device__ __forceinline__ float4 fma4(float a, float4 b, float4 c) {
  return make_float4(fmaf(a, b.x, c.x), fmaf(a, b.y, c.y),
                     fmaf(a, b.z, c.z), fmaf(a, b.w, c.w));
}

// ---- A1: per-wg bucket histogram ------------------------------------------
__global__ __launch_bounds__(256) void bucket_hist_kernel(
    const int* __restrict__ dst, int E, int chunk, int NBUK,
    int* __restrict__ M /* [NBUK][NWGA] */) {
  __shared__ int hist[512];
  const int w = blockIdx.x, t = threadIdx.x;
  for (int i = t; i < NBUK; i += 256) hist[i] = 0;
  __syncthreads();
  const int e0 = w * chunk;
  const int e1 = min(e0 + chunk, E);
  for (int e = e0 + t; e < e1; e += 256) atomicAdd(&hist[dst[e] >> 8], 1);
  __syncthreads();
  for (int i = t; i < NBUK; i += 256) M[i * NWGA + w] = hist[i];
}

// ---- scan helpers ---------------------------------------------------------
__global__ void scan_blocksum(const int* __restrict__ data, int len,
                              int* __restrict__ bsum) {
  __shared__ int s[256];
  int i = blockIdx.x * 256 + threadIdx.x;
  s[threadIdx.x] = (i < len) ? data[i] : 0;
  __syncthreads();
  for (int off = 128; off > 0; off >>= 1) {
    if (threadIdx.x < off) s[threadIdx.x] += s[threadIdx.x + off];
    __syncthreads();
  }
  if (threadIdx.x == 0) bsum[blockIdx.x] = s[0];
}

__global__ void scan_bsums(int* bsum, int NB) {
  __shared__ int s[512];
  int t = threadIdx.x;
  int v = (t < NB) ? bsum[t] : 0;
  s[t] = v;
  __syncthreads();
  for (int off = 1; off < 512; off <<= 1) {
    int u = (t >= off) ? s[t - off] : 0;
    __syncthreads();
    s[t] += u;
    __syncthreads();
  }
  if (t < NB) bsum[t] = s[t] - v;  // exclusive block base
}

__global__ void scan_final(int* __restrict__ data, int len,
                           const int* __restrict__ bsum) {
  __shared__ int s[256];
  int t = threadIdx.x;
  int i = blockIdx.x * 256 + t;
  int v = (i < len) ? data[i] : 0;
  s[t] = v;
  __syncthreads();
  for (int off = 1; off < 256; off <<= 1) {
    int u = (t >= off) ? s[t - off] : 0;
    __syncthreads();
    s[t] += u;
    __syncthreads();
  }
  if (i < len) data[i] = bsum[blockIdx.x] + s[t] - v;  // exclusive, in-place
}

// ---- A2: scatter edges into reserved contiguous bucket runs ---------------
__global__ __launch_bounds__(256) void bucket_scatter_kernel(
    const int* __restrict__ ei, int E, int chunk, int NBUK,
    const int* __restrict__ Mscan, int2* __restrict__ edata1) {
  __shared__ int cur[512];
  const int w = blockIdx.x, t = threadIdx.x;
  for (int i = t; i < NBUK; i += 256) cur[i] = Mscan[i * NWGA + w];
  __syncthreads();
  const int e0 = w * chunk;
  const int e1 = min(e0 + chunk, E);
  for (int e = e0 + t; e < e1; e += 256) {
    int s = ei[e];
    int d = ei[E + e];
    int pos = atomicAdd(&cur[d >> 8], 1);
    edata1[pos] = make_int2(s, d);
  }
}

// ---- B: per-bucket exact counting sort -> CSR offsets, dinv, src list -----
__global__ __launch_bounds__(256) void bucket_sort_kernel(
    const int2* __restrict__ edata1, const int* __restrict__ Mscan, int E,
    int N, int NBUK, int* __restrict__ offsets, float* __restrict__ dinv,
    int* __restrict__ edata2) {
  __shared__ int hist[256];
  __shared__ int cursor[256];
  const int b = blockIdx.x, t = threadIdx.x;
  const int base = Mscan[b * NWGA];
  const int end = (b + 1 < NBUK) ? Mscan[(b + 1) * NWGA] : E;
  const int nodebase = b << 8;
  hist[t] = 0;
  __syncthreads();
  for (int e = base + t; e < end; e += 256)
    atomicAdd(&hist[edata1[e].y - nodebase], 1);
  __syncthreads();
  const int deg = hist[t];
  for (int off = 1; off < 256; off <<= 1) {  // inclusive scan
    int u = (t >= off) ? hist[t - off] : 0;
    __syncthreads();
    hist[t] += u;
    __syncthreads();
  }
  const int excl = hist[t] - deg;
  const int node = nodebase + t;
  cursor[t] = base + excl;
  if (node < N) {
    offsets[node] = base + excl;
    dinv[node] = rsqrtf((float)(deg + 1));  // +1 self-loop
  }
  if (node == N - 1) offsets[N] = E;
  __syncthreads();
  for (int e = base + t; e < end; e += 256) {
    int2 sd = edata1[e];
    int pos = atomicAdd(&cursor[sd.y - nodebase], 1);
    edata2[pos] = sd.x;
  }
}

// ---- GEMM: H[N,D] = X[N,K] @ W[K,D] (+bias,relu); W staged in LDS ---------
template <int K, int D, bool BR, typename OutT>
__global__ __launch_bounds__(256) void gemm_kernel(
    const float* __restrict__ X, const float* __restrict__ W,
    const float* __restrict__ bias, OutT* __restrict__ H, int N) {
  constexpr int CG = D / 4;
  constexpr int TY = 256 / CG;
  constexpr int ROWS = TY * 4;
  __shared__ float Ws[K * D];
  for (int i = threadIdx.x; i < K * D / 4; i += 256)
    reinterpret_cast<float4*>(Ws)[i] = reinterpret_cast<const float4*>(W)[i];
  __syncthreads();

  const int tx = threadIdx.x % CG;
  const int ty = threadIdx.x / CG;
  const int rbase = blockIdx.x * ROWS + ty;

  float4 acc[4];
  int r[4];
#pragma unroll
  for (int i = 0; i < 4; i++) {
    acc[i] = make_float4(0.f, 0.f, 0.f, 0.f);
    int rr = rbase + i * TY;
    r[i] = (rr < N) ? rr : (N - 1);
  }

  for (int k = 0; k < K; k += 4) {
    float4 wv0 = *reinterpret_cast<const float4*>(&Ws[(k + 0) * D + tx * 4]);
    float4 wv1 = *reinterpret_cast<const float4*>(&Ws[(k + 1) * D + tx * 4]);
    float4 wv2 = *reinterpret_cast<const float4*>(&Ws[(k + 2) * D + tx * 4]);
    float4 wv3 = *reinterpret_cast<const float4*>(&Ws[(k + 3) * D + tx * 4]);
#pragma unroll
    for (int i = 0; i < 4; i++) {
      float4 xv = *reinterpret_cast<const float4*>(&X[(size_t)r[i] * K + k]);
      acc[i] = fma4(xv.x, wv0, acc[i]);
      acc[i] = fma4(xv.y, wv1, acc[i]);
      acc[i] = fma4(xv.z, wv2, acc[i]);
      acc[i] = fma4(xv.w, wv3, acc[i]);
    }
  }

  float4 bv = make_float4(0.f, 0.f, 0.f, 0.f);
  if (BR) bv = *reinterpret_cast<const float4*>(&bias[tx * 4]);

#pragma unroll
  for (int i = 0; i < 4; i++) {
    int rr = rbase + i * TY;
    if (rr < N) {
      float4 v = acc[i];
      if (BR) {
        v.x = fmaxf(v.x + bv.x, 0.f);
        v.y = fmaxf(v.y + bv.y, 0.f);
        v.z = fmaxf(v.z + bv.z, 0.f);
        v.w = fmaxf(v.w + bv.w, 0.f);
      }
      if constexpr (sizeof(OutT) == 2) {
        Half4 hv = {__float2half(v.x), __float2half(v.y), __float2half(v.z),
                    __float2half(v.w)};
        *reinterpret_cast<Half4*>(&H[(size_t)rr * D + tx * 4]) = hv;
      } else {
        *reinterpret_cast<float4*>(&H[(size_t)rr * D + tx * 4]) = v;
      }
    }
  }
}

// ---- Aggregation (D=64): one 64-lane wave per node, fp16 gather table -----
// out[n] = post( dinv[n]^2*h[n] + sum_e dinv[src]*dinv[n]*h[src] )
template <bool BIAS, bool RELU, typename OutT>
__global__ __launch_bounds__(256) void agg_kernel(
    const __half* __restrict__ h, const int* __restrict__ edata,
    const int* __restrict__ offsets, const float* __restrict__ dinv,
    const float* __restrict__ bias, OutT* __restrict__ out, int N) {
  int node = blockIdx.x * (blockDim.x >> 6) + (threadIdx.x >> 6);
  if (node >= N) return;
  int lane = threadIdx.x & 63;

  float dn = dinv[node];
  float acc = __half2float(h[(size_t)node * 64 + lane]) * dn * dn;

  int e = offsets[node];
  const int e1 = offsets[node + 1];

  for (; e + 4 <= e1; e += 4) {
    int s0 = edata[e + 0];
    int s1 = edata[e + 1];
    int s2 = edata[e + 2];
    int s3 = edata[e + 3];
    float w0 = dinv[s0] * dn;
    float w1 = dinv[s1] * dn;
    float w2 = dinv[s2] * dn;
    float w3 = dinv[s3] * dn;
    float g0 = __half2float(h[(size_t)s0 * 64 + lane]);
    float g1 = __half2float(h[(size_t)s1 * 64 + lane]);
    float g2 = __half2float(h[(size_t)s2 * 64 + lane]);
    float g3 = __half2float(h[(size_t)s3 * 64 + lane]);
    acc = fmaf(g0, w0, acc);
    acc = fmaf(g1, w1, acc);
    acc = fmaf(g2, w2, acc);
    acc = fmaf(g3, w3, acc);
  }
  for (; e < e1; ++e) {
    int s = edata[e];
    acc = fmaf(__half2float(h[(size_t)s * 64 + lane]), dinv[s] * dn, acc);
  }

  float v = acc;
  if (BIAS) v += bias[lane];
  if (RELU) v = fmaxf(v, 0.f);
  if constexpr (sizeof(OutT) == 2)
    out[(size_t)node * 64 + lane] = __float2half(v);
  else
    out[(size_t)node * 64 + lane] = v;
}

extern "C" void kernel_launch(void* const* d_in, const int* in_sizes, int n_in,
                              void* d_out, int out_size, void* d_ws,
                              size_t ws_size, hipStream_t stream) {
  const float* x  = (const float*)d_in[0];
  const int*   ei = (const int*)d_in[1];
  const float* W1 = (const float*)d_in[2];
  const float* b1 = (const float*)d_in[3];
  const float* W2 = (const float*)d_in[4];
  const float* b2 = (const float*)d_in[5];
  const float* W3 = (const float*)d_in[6];
  const float* b3 = (const float*)d_in[7];

  const int N = in_sizes[0] / 128;
  const int E = in_sizes[1] / 2;
  const int NBUK = (N + 255) >> 8;          // 391 for N=100000
  const int MLEN = NBUK * NWGA;             // 100096
  const int chunk = (E + NWGA - 1) / NWGA;  // 6250

  // Workspace carve-out (~103 MB)
  char* w = (char*)d_ws;
  int* M = (int*)w;            w += (size_t)MLEN * 4;
  int* bsum = (int*)w;         w += 512 * 4;
  int* offsets = (int*)w;      w += (size_t)(N + 2) * 4;
  float* dinv = (float*)w;     w += (size_t)N * 4;
  int* edata2 = (int*)w;       w += (size_t)E * 4;
  w = (char*)(((uintptr_t)w + 255) & ~(uintptr_t)255);
  __half* ht1 = (__half*)w;    w += (size_t)N * 64 * 2;   // t1 / t3 table
  __half* hout1 = (__half*)w;  w += (size_t)N * 64 * 2;   // out1 table
  w = (char*)(((uintptr_t)w + 255) & ~(uintptr_t)255);
  float* a2 = (float*)w;       w += (size_t)N * 64 * 4;   // Agg(out1)
  float* h2 = (float*)w;       w += (size_t)N * 128 * 4;  // layer-2 output
  int2* edata1 = (int2*)h2;    // alias: build-phase only (E*8 <= N*128*4)

  const int NBS = (MLEN + 255) / 256;  // 391 (<=512)

  // ---- CSR build ----
  bucket_hist_kernel<<<NWGA, 256, 0, stream>>>(ei + E, E, chunk, NBUK, M);
  scan_blocksum<<<NBS, 256, 0, stream>>>(M, MLEN, bsum);
  scan_bsums<<<1, 512, 0, stream>>>(bsum, NBS);
  scan_final<<<NBS, 256, 0, stream>>>(M, MLEN, bsum);
  bucket_scatter_kernel<<<NWGA, 256, 0, stream>>>(ei, E, chunk, NBUK, M, edata1);
  bucket_sort_kernel<<<NBUK, 256, 0, stream>>>(edata1, M, E, N, NBUK, offsets,
                                               dinv, edata2);

  // ---- Layer 1: t1 = x@W1 (fp16) ; out1 = relu(Agg(t1)+b1) (fp16) ----
  gemm_kernel<128, 64, false, __half><<<(N + 63) / 64, 256, 0, stream>>>(
      x, W1, nullptr, ht1, N);
  agg_kernel<true, true, __half><<<(N + 3) / 4, 256, 0, stream>>>(
      ht1, edata2, offsets, dinv, b1, hout1, N);

  // ---- Layer 2: a2 = Agg(out1) (fp32) ; h2 = relu(a2@W2+b2) (fp32) ----
  agg_kernel<false, false, float><<<(N + 3) / 4, 256, 0, stream>>>(
      hout1, edata2, offsets, dinv, nullptr, a2, N);
  gemm_kernel<64, 128, true, float><<<(N + 31) / 32, 256, 0, stream>>>(
      a2, W2, b2, h2, N);

  // ---- Layer 3: t3 = h2@W3 (fp16) ; out = Agg(t3)+b3 (fp32) ----
  gemm_kernel<128, 64, false, __half><<<(N + 63) / 64, 256, 0, stream>>>(
      h2, W3, nullptr, ht1, N);
  agg_kernel<true, false, float><<<(N + 3) / 4, 256, 0, stream>>>(
      ht1, edata2, offsets, dinv, b3, (float*)d_out, N);
}

// Round 4
// 426.282 us; speedup vs baseline: 1.4783x; 1.0796x over previous
//
#include <hip/hip_runtime.h>
#include <hip/hip_fp16.h>
#include <stdint.h>

// ---------------------------------------------------------------------------
// GCN 3-layer forward on MI355X.
// CSR build: 3-phase bucket sort; then edge_weight pass packs {src,dinv[src]}
// per edge (8B) so agg has ONE random stream (row gather) + sequential edges.
// Layers use A(XW) = (AX)W so all aggregations run at D=64 over fp16 tables:
//   t1 = x@W1 (fp16)      ; out1 = relu(Agg(t1)+b1)  (fp16)
//   a2 = Agg(out1) (fp32) ; h2   = relu(a2@W2+b2)    (fp32)
//   t3 = h2@W3 (fp16)     ; out  = Agg(t3)+b3        (fp32)
// ---------------------------------------------------------------------------

#define NWGA 256  // workgroups for edge-chunk passes

struct __align__(8) Half4 { __half x, y, z, w; };

__device__ __forceinline__ float4 fma4(float a, float4 b, float4 c) {
  return make_float4(fmaf(a, b.x, c.x), fmaf(a, b.y, c.y),
                     fmaf(a, b.z, c.z), fmaf(a, b.w, c.w));
}

// ---- A1: per-wg bucket histogram ------------------------------------------
__global__ __launch_bounds__(256) void bucket_hist_kernel(
    const int* __restrict__ dst, int E, int chunk, int NBUK,
    int* __restrict__ M /* [NBUK][NWGA] */) {
  __shared__ int hist[512];
  const int w = blockIdx.x, t = threadIdx.x;
  for (int i = t; i < NBUK; i += 256) hist[i] = 0;
  __syncthreads();
  const int e0 = w * chunk;
  const int e1 = min(e0 + chunk, E);
  for (int e = e0 + t; e < e1; e += 256) atomicAdd(&hist[dst[e] >> 8], 1);
  __syncthreads();
  for (int i = t; i < NBUK; i += 256) M[i * NWGA + w] = hist[i];
}

// ---- scan helpers ---------------------------------------------------------
__global__ void scan_blocksum(const int* __restrict__ data, int len,
                              int* __restrict__ bsum) {
  __shared__ int s[256];
  int i = blockIdx.x * 256 + threadIdx.x;
  s[threadIdx.x] = (i < len) ? data[i] : 0;
  __syncthreads();
  for (int off = 128; off > 0; off >>= 1) {
    if (threadIdx.x < off) s[threadIdx.x] += s[threadIdx.x + off];
    __syncthreads();
  }
  if (threadIdx.x == 0) bsum[blockIdx.x] = s[0];
}

__global__ void scan_bsums(int* bsum, int NB) {
  __shared__ int s[512];
  int t = threadIdx.x;
  int v = (t < NB) ? bsum[t] : 0;
  s[t] = v;
  __syncthreads();
  for (int off = 1; off < 512; off <<= 1) {
    int u = (t >= off) ? s[t - off] : 0;
    __syncthreads();
    s[t] += u;
    __syncthreads();
  }
  if (t < NB) bsum[t] = s[t] - v;  // exclusive block base
}

__global__ void scan_final(int* __restrict__ data, int len,
                           const int* __restrict__ bsum) {
  __shared__ int s[256];
  int t = threadIdx.x;
  int i = blockIdx.x * 256 + t;
  int v = (i < len) ? data[i] : 0;
  s[t] = v;
  __syncthreads();
  for (int off = 1; off < 256; off <<= 1) {
    int u = (t >= off) ? s[t - off] : 0;
    __syncthreads();
    s[t] += u;
    __syncthreads();
  }
  if (i < len) data[i] = bsum[blockIdx.x] + s[t] - v;  // exclusive, in-place
}

// ---- A2: scatter edges into reserved contiguous bucket runs ---------------
__global__ __launch_bounds__(256) void bucket_scatter_kernel(
    const int* __restrict__ ei, int E, int chunk, int NBUK,
    const int* __restrict__ Mscan, int2* __restrict__ edata1) {
  __shared__ int cur[512];
  const int w = blockIdx.x, t = threadIdx.x;
  for (int i = t; i < NBUK; i += 256) cur[i] = Mscan[i * NWGA + w];
  __syncthreads();
  const int e0 = w * chunk;
  const int e1 = min(e0 + chunk, E);
  for (int e = e0 + t; e < e1; e += 256) {
    int s = ei[e];
    int d = ei[E + e];
    int pos = atomicAdd(&cur[d >> 8], 1);
    edata1[pos] = make_int2(s, d);
  }
}

// ---- B: per-bucket exact counting sort -> CSR offsets, dinv, src list -----
__global__ __launch_bounds__(256) void bucket_sort_kernel(
    const int2* __restrict__ edata1, const int* __restrict__ Mscan, int E,
    int N, int NBUK, int* __restrict__ offsets, float* __restrict__ dinv,
    int* __restrict__ edata2) {
  __shared__ int hist[256];
  __shared__ int cursor[256];
  const int b = blockIdx.x, t = threadIdx.x;
  const int base = Mscan[b * NWGA];
  const int end = (b + 1 < NBUK) ? Mscan[(b + 1) * NWGA] : E;
  const int nodebase = b << 8;
  hist[t] = 0;
  __syncthreads();
  for (int e = base + t; e < end; e += 256)
    atomicAdd(&hist[edata1[e].y - nodebase], 1);
  __syncthreads();
  const int deg = hist[t];
  for (int off = 1; off < 256; off <<= 1) {  // inclusive scan
    int u = (t >= off) ? hist[t - off] : 0;
    __syncthreads();
    hist[t] += u;
    __syncthreads();
  }
  const int excl = hist[t] - deg;
  const int node = nodebase + t;
  cursor[t] = base + excl;
  if (node < N) {
    offsets[node] = base + excl;
    dinv[node] = rsqrtf((float)(deg + 1));  // +1 self-loop
  }
  if (node == N - 1) offsets[N] = E;
  __syncthreads();
  for (int e = base + t; e < end; e += 256) {
    int2 sd = edata1[e];
    int pos = atomicAdd(&cursor[sd.y - nodebase], 1);
    edata2[pos] = sd.x;
  }
}

// ---- C: pack per-edge {src, dinv[src]} ------------------------------------
__global__ __launch_bounds__(256) void edge_weight_kernel(
    const int* __restrict__ edata2, const float* __restrict__ dinv, int E,
    int2* __restrict__ ed3) {
  int stride = gridDim.x * blockDim.x;
  for (int e = blockIdx.x * blockDim.x + threadIdx.x; e < E; e += stride) {
    int s = edata2[e];
    ed3[e] = make_int2(s, __float_as_int(dinv[s]));
  }
}

// ---- GEMM: H[N,D] = X[N,K] @ W[K,D] (+bias,relu); W staged in LDS ---------
template <int K, int D, bool BR, typename OutT>
__global__ __launch_bounds__(256) void gemm_kernel(
    const float* __restrict__ X, const float* __restrict__ W,
    const float* __restrict__ bias, OutT* __restrict__ H, int N) {
  constexpr int CG = D / 4;
  constexpr int TY = 256 / CG;
  constexpr int ROWS = TY * 4;
  __shared__ float Ws[K * D];
  for (int i = threadIdx.x; i < K * D / 4; i += 256)
    reinterpret_cast<float4*>(Ws)[i] = reinterpret_cast<const float4*>(W)[i];
  __syncthreads();

  const int tx = threadIdx.x % CG;
  const int ty = threadIdx.x / CG;
  const int rbase = blockIdx.x * ROWS + ty;

  float4 acc[4];
  int r[4];
#pragma unroll
  for (int i = 0; i < 4; i++) {
    acc[i] = make_float4(0.f, 0.f, 0.f, 0.f);
    int rr = rbase + i * TY;
    r[i] = (rr < N) ? rr : (N - 1);
  }

  for (int k = 0; k < K; k += 4) {
    float4 wv0 = *reinterpret_cast<const float4*>(&Ws[(k + 0) * D + tx * 4]);
    float4 wv1 = *reinterpret_cast<const float4*>(&Ws[(k + 1) * D + tx * 4]);
    float4 wv2 = *reinterpret_cast<const float4*>(&Ws[(k + 2) * D + tx * 4]);
    float4 wv3 = *reinterpret_cast<const float4*>(&Ws[(k + 3) * D + tx * 4]);
#pragma unroll
    for (int i = 0; i < 4; i++) {
      float4 xv = *reinterpret_cast<const float4*>(&X[(size_t)r[i] * K + k]);
      acc[i] = fma4(xv.x, wv0, acc[i]);
      acc[i] = fma4(xv.y, wv1, acc[i]);
      acc[i] = fma4(xv.z, wv2, acc[i]);
      acc[i] = fma4(xv.w, wv3, acc[i]);
    }
  }

  float4 bv = make_float4(0.f, 0.f, 0.f, 0.f);
  if (BR) bv = *reinterpret_cast<const float4*>(&bias[tx * 4]);

#pragma unroll
  for (int i = 0; i < 4; i++) {
    int rr = rbase + i * TY;
    if (rr < N) {
      float4 v = acc[i];
      if (BR) {
        v.x = fmaxf(v.x + bv.x, 0.f);
        v.y = fmaxf(v.y + bv.y, 0.f);
        v.z = fmaxf(v.z + bv.z, 0.f);
        v.w = fmaxf(v.w + bv.w, 0.f);
      }
      if constexpr (sizeof(OutT) == 2) {
        Half4 hv = {__float2half(v.x), __float2half(v.y), __float2half(v.z),
                    __float2half(v.w)};
        *reinterpret_cast<Half4*>(&H[(size_t)rr * D + tx * 4]) = hv;
      } else {
        *reinterpret_cast<float4*>(&H[(size_t)rr * D + tx * 4]) = v;
      }
    }
  }
}

// ---- Aggregation (D=64): one 64-lane wave per node, 8-deep gather MLP -----
// out[n] = post( dn*( dn*h[n] + sum_e dinv[src]*h[src] ) )
template <bool BIAS, bool RELU, typename OutT>
__global__ __launch_bounds__(256) void agg_kernel(
    const __half* __restrict__ h, const int2* __restrict__ ed,
    const int* __restrict__ offsets, const float* __restrict__ dinv,
    const float* __restrict__ bias, OutT* __restrict__ out, int N) {
  int node = blockIdx.x * 4 + (threadIdx.x >> 6);
  if (node >= N) return;
  const int lane = threadIdx.x & 63;

  const float dn = dinv[node];
  float acc = __half2float(h[(size_t)node * 64 + lane]) * dn;

  int e = offsets[node];
  const int e1 = offsets[node + 1];

  for (; e + 8 <= e1; e += 8) {
    int2 p0 = ed[e + 0];
    int2 p1 = ed[e + 1];
    int2 p2 = ed[e + 2];
    int2 p3 = ed[e + 3];
    int2 p4 = ed[e + 4];
    int2 p5 = ed[e + 5];
    int2 p6 = ed[e + 6];
    int2 p7 = ed[e + 7];
    float g0 = __half2float(h[(size_t)p0.x * 64 + lane]);
    float g1 = __half2float(h[(size_t)p1.x * 64 + lane]);
    float g2 = __half2float(h[(size_t)p2.x * 64 + lane]);
    float g3 = __half2float(h[(size_t)p3.x * 64 + lane]);
    float g4 = __half2float(h[(size_t)p4.x * 64 + lane]);
    float g5 = __half2float(h[(size_t)p5.x * 64 + lane]);
    float g6 = __half2float(h[(size_t)p6.x * 64 + lane]);
    float g7 = __half2float(h[(size_t)p7.x * 64 + lane]);
    acc = fmaf(g0, __int_as_float(p0.y), acc);
    acc = fmaf(g1, __int_as_float(p1.y), acc);
    acc = fmaf(g2, __int_as_float(p2.y), acc);
    acc = fmaf(g3, __int_as_float(p3.y), acc);
    acc = fmaf(g4, __int_as_float(p4.y), acc);
    acc = fmaf(g5, __int_as_float(p5.y), acc);
    acc = fmaf(g6, __int_as_float(p6.y), acc);
    acc = fmaf(g7, __int_as_float(p7.y), acc);
  }
  if (e + 4 <= e1) {
    int2 p0 = ed[e + 0];
    int2 p1 = ed[e + 1];
    int2 p2 = ed[e + 2];
    int2 p3 = ed[e + 3];
    float g0 = __half2float(h[(size_t)p0.x * 64 + lane]);
    float g1 = __half2float(h[(size_t)p1.x * 64 + lane]);
    float g2 = __half2float(h[(size_t)p2.x * 64 + lane]);
    float g3 = __half2float(h[(size_t)p3.x * 64 + lane]);
    acc = fmaf(g0, __int_as_float(p0.y), acc);
    acc = fmaf(g1, __int_as_float(p1.y), acc);
    acc = fmaf(g2, __int_as_float(p2.y), acc);
    acc = fmaf(g3, __int_as_float(p3.y), acc);
    e += 4;
  }
  for (; e < e1; ++e) {
    int2 p = ed[e];
    acc = fmaf(__half2float(h[(size_t)p.x * 64 + lane]),
               __int_as_float(p.y), acc);
  }

  float v = acc * dn;
  if (BIAS) v += bias[lane];
  if (RELU) v = fmaxf(v, 0.f);
  if constexpr (sizeof(OutT) == 2)
    out[(size_t)node * 64 + lane] = __float2half(v);
  else
    out[(size_t)node * 64 + lane] = v;
}

extern "C" void kernel_launch(void* const* d_in, const int* in_sizes, int n_in,
                              void* d_out, int out_size, void* d_ws,
                              size_t ws_size, hipStream_t stream) {
  const float* x  = (const float*)d_in[0];
  const int*   ei = (const int*)d_in[1];
  const float* W1 = (const float*)d_in[2];
  const float* b1 = (const float*)d_in[3];
  const float* W2 = (const float*)d_in[4];
  const float* b2 = (const float*)d_in[5];
  const float* W3 = (const float*)d_in[6];
  const float* b3 = (const float*)d_in[7];

  const int N = in_sizes[0] / 128;
  const int E = in_sizes[1] / 2;
  const int NBUK = (N + 255) >> 8;          // 391 for N=100000
  const int MLEN = NBUK * NWGA;             // 100096
  const int chunk = (E + NWGA - 1) / NWGA;  // 6250

  // Workspace (~103 MB) with lifetime-based aliasing:
  //  perm   : offsets, dinv, edata3
  //  regionA: {M, bsum, edata2}(build)          -> ht1 (t1/t3 fp16 table)
  //  regionB: edata1(build)                     -> a2  (Agg(out1), fp32)
  //  regionC: hout1 (fp16, agg1->agg2)          -> h2  (fp32, gemm2->gemm3)
  char* w = (char*)d_ws;
  int* offsets = (int*)w;      w += (size_t)(N + 2) * 4;
  float* dinv = (float*)w;     w += (size_t)N * 4;
  w = (char*)(((uintptr_t)w + 255) & ~(uintptr_t)255);
  int2* edata3 = (int2*)w;     w += (size_t)E * 8;
  w = (char*)(((uintptr_t)w + 255) & ~(uintptr_t)255);
  char* regionA = w;           w += (size_t)N * 64 * 2;   // 12.8 MB
  w = (char*)(((uintptr_t)w + 255) & ~(uintptr_t)255);
  char* regionB = w;           w += (size_t)N * 64 * 4;   // 25.6 MB
  w = (char*)(((uintptr_t)w + 255) & ~(uintptr_t)255);
  char* regionC = w;           w += (size_t)N * 128 * 4;  // 51.2 MB

  int* M = (int*)regionA;                       // MLEN*4 = 0.4 MB
  int* bsum = M + MLEN;                         // 2 KB
  int* edata2 = bsum + 512;                     // E*4 = 6.4 MB (tot 6.8 <=12.8)
  __half* ht1 = (__half*)regionA;               // after edge_weight
  int2* edata1 = (int2*)regionB;                // E*8 = 12.8 <= 25.6
  float* a2 = (float*)regionB;                  // after bucket_sort
  __half* hout1 = (__half*)regionC;             // agg1 -> agg2
  float* h2 = (float*)regionC;                  // gemm2 -> gemm3

  const int NBS = (MLEN + 255) / 256;  // 391 (<=512)

  // ---- CSR build ----
  bucket_hist_kernel<<<NWGA, 256, 0, stream>>>(ei + E, E, chunk, NBUK, M);
  scan_blocksum<<<NBS, 256, 0, stream>>>(M, MLEN, bsum);
  scan_bsums<<<1, 512, 0, stream>>>(bsum, NBS);
  scan_final<<<NBS, 256, 0, stream>>>(M, MLEN, bsum);
  bucket_scatter_kernel<<<NWGA, 256, 0, stream>>>(ei, E, chunk, NBUK, M, edata1);
  bucket_sort_kernel<<<NBUK, 256, 0, stream>>>(edata1, M, E, N, NBUK, offsets,
                                               dinv, edata2);
  edge_weight_kernel<<<1024, 256, 0, stream>>>(edata2, dinv, E, edata3);

  // ---- Layer 1: t1 = x@W1 (fp16) ; out1 = relu(Agg(t1)+b1) (fp16) ----
  gemm_kernel<128, 64, false, __half><<<(N + 63) / 64, 256, 0, stream>>>(
      x, W1, nullptr, ht1, N);
  agg_kernel<true, true, __half><<<(N + 3) / 4, 256, 0, stream>>>(
      ht1, edata3, offsets, dinv, b1, hout1, N);

  // ---- Layer 2: a2 = Agg(out1) (fp32) ; h2 = relu(a2@W2+b2) (fp32) ----
  agg_kernel<false, false, float><<<(N + 3) / 4, 256, 0, stream>>>(
      hout1, edata3, offsets, dinv, nullptr, a2, N);
  gemm_kernel<64, 128, true, float><<<(N + 31) / 32, 256, 0, stream>>>(
      a2, W2, b2, h2, N);

  // ---- Layer 3: t3 = h2@W3 (fp16) ; out = Agg(t3)+b3 (fp32) ----
  gemm_kernel<128, 64, false, __half><<<(N + 63) / 64, 256, 0, stream>>>(
      h2, W3, nullptr, ht1, N);
  agg_kernel<true, false, float><<<(N + 3) / 4, 256, 0, stream>>>(
      ht1, edata3, offsets, dinv, b3, (float*)d_out, N);
}

// Round 5
// 377.885 us; speedup vs baseline: 1.6676x; 1.1281x over previous
//
#include <hip/hip_runtime.h>
#include <hip/hip_fp16.h>
#include <stdint.h>

// ---------------------------------------------------------------------------
// GCN 3-layer forward on MI355X.
// CSR build (bucket sort) now inserts SELF-LOOP edges, so aggregation is a
// pure weighted gather-sum. Weights dinv[src] are pre-folded into the fp16
// gather tables by the producing GEMM/agg epilogue, so the edge stream is a
// 4B row-byte-offset. Aggregation: one wave per 8 consecutive nodes = one
// contiguous edge run; edge indices pre-loaded lane-spread and broadcast via
// __shfl (lgkmcnt) so the 8-deep gather pipeline (vmcnt) never drains.
//   t1' = dinv*(x@W1) (fp16)   ; out1' = dinv*relu(dn*Agg(t1')+b1) (fp16)
//   a2  = dn*Agg(out1') (fp16) ; h2 = relu(a2@W2+b2) (fp16)
//   t3' = dinv*(h2@W3) (fp16)  ; out = dn*Agg(t3')+b3 (fp32)
// ---------------------------------------------------------------------------

#define NWGA 256  // workgroups for edge-chunk passes
#define CMAX 8    // max 64-edge chunks per wave (8 nodes, cap 512 edges)

struct __align__(8) Half4 { __half x, y, z, w; };

__device__ __forceinline__ float4 fma4(float a, float4 b, float4 c) {
  return make_float4(fmaf(a, b.x, c.x), fmaf(a, b.y, c.y),
                     fmaf(a, b.z, c.z), fmaf(a, b.w, c.w));
}

// ---- A1: per-wg bucket histogram ------------------------------------------
__global__ __launch_bounds__(256) void bucket_hist_kernel(
    const int* __restrict__ dst, int E, int chunk, int NBUK,
    int* __restrict__ M /* [NBUK][NWGA] */) {
  __shared__ int hist[512];
  const int w = blockIdx.x, t = threadIdx.x;
  for (int i = t; i < NBUK; i += 256) hist[i] = 0;
  __syncthreads();
  const int e0 = w * chunk;
  const int e1 = min(e0 + chunk, E);
  for (int e = e0 + t; e < e1; e += 256) atomicAdd(&hist[dst[e] >> 8], 1);
  __syncthreads();
  for (int i = t; i < NBUK; i += 256) M[i * NWGA + w] = hist[i];
}

// ---- scan helpers ---------------------------------------------------------
__global__ void scan_blocksum(const int* __restrict__ data, int len,
                              int* __restrict__ bsum) {
  __shared__ int s[256];
  int i = blockIdx.x * 256 + threadIdx.x;
  s[threadIdx.x] = (i < len) ? data[i] : 0;
  __syncthreads();
  for (int off = 128; off > 0; off >>= 1) {
    if (threadIdx.x < off) s[threadIdx.x] += s[threadIdx.x + off];
    __syncthreads();
  }
  if (threadIdx.x == 0) bsum[blockIdx.x] = s[0];
}

__global__ void scan_bsums(int* bsum, int NB) {
  __shared__ int s[512];
  int t = threadIdx.x;
  int v = (t < NB) ? bsum[t] : 0;
  s[t] = v;
  __syncthreads();
  for (int off = 1; off < 512; off <<= 1) {
    int u = (t >= off) ? s[t - off] : 0;
    __syncthreads();
    s[t] += u;
    __syncthreads();
  }
  if (t < NB) bsum[t] = s[t] - v;  // exclusive block base
}

__global__ void scan_final(int* __restrict__ data, int len,
                           const int* __restrict__ bsum) {
  __shared__ int s[256];
  int t = threadIdx.x;
  int i = blockIdx.x * 256 + t;
  int v = (i < len) ? data[i] : 0;
  s[t] = v;
  __syncthreads();
  for (int off = 1; off < 256; off <<= 1) {
    int u = (t >= off) ? s[t - off] : 0;
    __syncthreads();
    s[t] += u;
    __syncthreads();
  }
  if (i < len) data[i] = bsum[blockIdx.x] + s[t] - v;  // exclusive, in-place
}

// ---- A2: scatter edges into reserved contiguous bucket runs ---------------
__global__ __launch_bounds__(256) void bucket_scatter_kernel(
    const int* __restrict__ ei, int E, int chunk, int NBUK,
    const int* __restrict__ Mscan, int2* __restrict__ edata1) {
  __shared__ int cur[512];
  const int w = blockIdx.x, t = threadIdx.x;
  for (int i = t; i < NBUK; i += 256) cur[i] = Mscan[i * NWGA + w];
  __syncthreads();
  const int e0 = w * chunk;
  const int e1 = min(e0 + chunk, E);
  for (int e = e0 + t; e < e1; e += 256) {
    int s = ei[e];
    int d = ei[E + e];
    int pos = atomicAdd(&cur[d >> 8], 1);
    edata1[pos] = make_int2(s, d);
  }
}

// ---- B: per-bucket counting sort; inserts self-loop as FIRST edge ---------
// Padded CSR: base_b = Mscan[b*NWGA] + min(b*256, N); offsets cover E+N.
__global__ __launch_bounds__(256) void bucket_sort_kernel(
    const int2* __restrict__ edata1, const int* __restrict__ Mscan, int E,
    int N, int NBUK, int* __restrict__ offsets, float* __restrict__ dinv,
    int* __restrict__ edata2) {
  __shared__ int hist[256];
  __shared__ int cursor[256];
  const int b = blockIdx.x, t = threadIdx.x;
  const int ebase = Mscan[b * NWGA];
  const int eend = (b + 1 < NBUK) ? Mscan[(b + 1) * NWGA] : E;
  const int nodebase = b << 8;
  const int node = nodebase + t;
  const int base = ebase + min(nodebase, N);  // + prior buckets' self-loops
  hist[t] = (node < N) ? 1 : 0;               // self-loop
  __syncthreads();
  for (int e = ebase + t; e < eend; e += 256)
    atomicAdd(&hist[edata1[e].y - nodebase], 1);
  __syncthreads();
  const int deg = hist[t];  // edges + self
  for (int off = 1; off < 256; off <<= 1) {  // inclusive scan
    int u = (t >= off) ? hist[t - off] : 0;
    __syncthreads();
    hist[t] += u;
    __syncthreads();
  }
  const int excl = hist[t] - deg;
  cursor[t] = base + excl + 1;  // slot 0 = self
  if (node < N) {
    offsets[node] = base + excl;
    dinv[node] = rsqrtf((float)deg);
    edata2[base + excl] = node;  // self edge
  }
  if (node == N - 1) offsets[N] = E + N;
  __syncthreads();
  for (int e = ebase + t; e < eend; e += 256) {
    int2 sd = edata1[e];
    int pos = atomicAdd(&cursor[sd.y - nodebase], 1);
    edata2[pos] = sd.x;
  }
}

// ---- C: per-edge row byte-offset (table rows are 128B fp16) ---------------
__global__ __launch_bounds__(256) void edge_weight_kernel(
    const int* __restrict__ edata2, int EN, int* __restrict__ ed3) {
  int stride = gridDim.x * blockDim.x;
  for (int e = blockIdx.x * blockDim.x + threadIdx.x; e < EN; e += stride)
    ed3[e] = edata2[e] << 7;
}

// ---- GEMM: H[N,D] = X[N,K] @ W[K,D] (+bias,relu / *dinv[row]) -------------
template <int K, int D, bool BR, bool DSCALE, typename InT, typename OutT>
__global__ __launch_bounds__(256) void gemm_kernel(
    const InT* __restrict__ X, const float* __restrict__ W,
    const float* __restrict__ bias, const float* __restrict__ dinv,
    OutT* __restrict__ H, int N) {
  constexpr int CG = D / 4;
  constexpr int TY = 256 / CG;
  constexpr int ROWS = TY * 4;
  __shared__ float Ws[K * D];
  for (int i = threadIdx.x; i < K * D / 4; i += 256)
    reinterpret_cast<float4*>(Ws)[i] = reinterpret_cast<const float4*>(W)[i];
  __syncthreads();

  const int tx = threadIdx.x % CG;
  const int ty = threadIdx.x / CG;
  const int rbase = blockIdx.x * ROWS + ty;

  float4 acc[4];
  int r[4];
#pragma unroll
  for (int i = 0; i < 4; i++) {
    acc[i] = make_float4(0.f, 0.f, 0.f, 0.f);
    int rr = rbase + i * TY;
    r[i] = (rr < N) ? rr : (N - 1);
  }

  for (int k = 0; k < K; k += 4) {
    float4 wv0 = *reinterpret_cast<const float4*>(&Ws[(k + 0) * D + tx * 4]);
    float4 wv1 = *reinterpret_cast<const float4*>(&Ws[(k + 1) * D + tx * 4]);
    float4 wv2 = *reinterpret_cast<const float4*>(&Ws[(k + 2) * D + tx * 4]);
    float4 wv3 = *reinterpret_cast<const float4*>(&Ws[(k + 3) * D + tx * 4]);
#pragma unroll
    for (int i = 0; i < 4; i++) {
      float4 xv;
      if constexpr (sizeof(InT) == 2) {
        Half4 xh = *reinterpret_cast<const Half4*>(&X[(size_t)r[i] * K + k]);
        xv = make_float4(__half2float(xh.x), __half2float(xh.y),
                         __half2float(xh.z), __half2float(xh.w));
      } else {
        xv = *reinterpret_cast<const float4*>(&X[(size_t)r[i] * K + k]);
      }
      acc[i] = fma4(xv.x, wv0, acc[i]);
      acc[i] = fma4(xv.y, wv1, acc[i]);
      acc[i] = fma4(xv.z, wv2, acc[i]);
      acc[i] = fma4(xv.w, wv3, acc[i]);
    }
  }

  float4 bv = make_float4(0.f, 0.f, 0.f, 0.f);
  if (BR) bv = *reinterpret_cast<const float4*>(&bias[tx * 4]);

#pragma unroll
  for (int i = 0; i < 4; i++) {
    int rr = rbase + i * TY;
    if (rr < N) {
      float4 v = acc[i];
      if (BR) {
        v.x = fmaxf(v.x + bv.x, 0.f);
        v.y = fmaxf(v.y + bv.y, 0.f);
        v.z = fmaxf(v.z + bv.z, 0.f);
        v.w = fmaxf(v.w + bv.w, 0.f);
      }
      if (DSCALE) {
        float ds = dinv[rr];
        v.x *= ds; v.y *= ds; v.z *= ds; v.w *= ds;
      }
      if constexpr (sizeof(OutT) == 2) {
        Half4 hv = {__float2half(v.x), __float2half(v.y), __float2half(v.z),
                    __float2half(v.w)};
        *reinterpret_cast<Half4*>(&H[(size_t)rr * D + tx * 4]) = hv;
      } else {
        *reinterpret_cast<float4*>(&H[(size_t)rr * D + tx * 4]) = v;
      }
    }
  }
}

// ---- Aggregation: wave = 8 consecutive nodes = 1 contiguous edge run ------
// Table rows pre-scaled by dinv[src]; self-loops are edges.
// flush: v = dn*acc (+bias) (relu); store (optionally *dn for next table).
template <bool BIAS, bool RELU, bool SCALE_OUT, typename OutT>
__global__ __launch_bounds__(256) void agg_kernel(
    const __half* __restrict__ h, const int* __restrict__ ed,
    const int* __restrict__ offsets, const float* __restrict__ dinv,
    const float* __restrict__ bias, OutT* __restrict__ out, int N) {
  const int wid = blockIdx.x * 4 + (threadIdx.x >> 6);
  const int na = wid * 8;
  if (na >= N) return;
  const int lane = threadIdx.x & 63;
  const int nrem = min(8, N - na);

  // lane-spread node metadata
  const int off_l = offsets[na + min(lane, nrem)];
  const float dn_l = dinv[na + min(lane, nrem - 1)];
  const int eb0 = __shfl(off_l, 0);
  const int eb1 = __shfl(off_l, nrem);
  float bsv = 0.f;
  if (BIAS) bsv = bias[lane];

  // pre-issue ALL edge-index loads, lane-spread (coalesced 256B each)
  int pe[CMAX];
#pragma unroll
  for (int c = 0; c < CMAX; ++c) {
    int idx = eb0 + c * 64 + lane;
    pe[c] = ed[min(idx, eb1 - 1)];
  }

  const char* hb = (const char*)h;
  float acc = 0.f;
  int cur = 0;
  int bnd = __shfl(off_l, 1);
  float dn = __shfl(dn_l, 0);
  int j = eb0;

#define FLUSH()                                                        \
  {                                                                    \
    float v = acc * dn;                                                \
    if (BIAS) v += bsv;                                                \
    if (RELU) v = fmaxf(v, 0.f);                                       \
    if (SCALE_OUT) v *= dn;                                            \
    if constexpr (sizeof(OutT) == 2)                                   \
      out[(size_t)(na + cur) * 64 + lane] = __float2half(v);           \
    else                                                               \
      out[(size_t)(na + cur) * 64 + lane] = v;                         \
    acc = 0.f;                                                         \
    cur++;                                                             \
    bnd = __shfl(off_l, min(cur + 1, 8));                              \
    dn = __shfl(dn_l, min(cur, 7));                                    \
  }

#pragma unroll
  for (int c = 0; c < CMAX; ++c) {
    if (j < eb1) {
      const int pc = pe[c];  // static index
      for (int k = 0; k < 64; k += 8) {
        if (j >= eb1) break;
        int so[8];
        float g[8], wv[8];
#pragma unroll
        for (int i = 0; i < 8; ++i) {
          so[i] = __shfl(pc, k + i);
          wv[i] = (j + i < eb1) ? 1.f : 0.f;
        }
#pragma unroll
        for (int i = 0; i < 8; ++i)
          g[i] = __half2float(
              *(const __half*)(hb + (size_t)(unsigned)so[i] + lane * 2));
#pragma unroll
        for (int i = 0; i < 8; ++i) {
          if (j + i == bnd) FLUSH();
          acc = fmaf(g[i], wv[i], acc);
        }
        j += 8;
      }
    }
  }
  // fallback for ranges > CMAX*64 edges (statistically never at deg~17)
  for (; j < eb1; ++j) {
    int so = ed[j];
    float g =
        __half2float(*(const __half*)(hb + (size_t)(unsigned)so + lane * 2));
    if (j == bnd) FLUSH();
    acc += g;
  }
  if (cur < nrem) FLUSH();
#undef FLUSH
}

extern "C" void kernel_launch(void* const* d_in, const int* in_sizes, int n_in,
                              void* d_out, int out_size, void* d_ws,
                              size_t ws_size, hipStream_t stream) {
  const float* x  = (const float*)d_in[0];
  const int*   ei = (const int*)d_in[1];
  const float* W1 = (const float*)d_in[2];
  const float* b1 = (const float*)d_in[3];
  const float* W2 = (const float*)d_in[4];
  const float* b2 = (const float*)d_in[5];
  const float* W3 = (const float*)d_in[6];
  const float* b3 = (const float*)d_in[7];

  const int N = in_sizes[0] / 128;
  const int E = in_sizes[1] / 2;
  const int EN = E + N;
  const int NBUK = (N + 255) >> 8;          // 391 for N=100000
  const int MLEN = NBUK * NWGA;             // 100096
  const int chunk = (E + NWGA - 1) / NWGA;  // 6250

  // Workspace (~60 MB) with lifetime aliasing:
  //  perm   : offsets, dinv, edata3(EN ints)
  //  regionA: {M, bsum, edata2}(build) -> ht1 (t1'/t3' fp16 table)
  //  regionB: edata1(build)            -> a2 (fp16)
  //  regionC: hout1 (fp16)             -> h2 (fp16)
  char* w = (char*)d_ws;
  int* offsets = (int*)w;      w += (size_t)(N + 2) * 4;
  float* dinv = (float*)w;     w += (size_t)N * 4;
  w = (char*)(((uintptr_t)w + 255) & ~(uintptr_t)255);
  int* edata3 = (int*)w;       w += (size_t)EN * 4;
  w = (char*)(((uintptr_t)w + 255) & ~(uintptr_t)255);
  char* regionA = w;           w += (size_t)N * 64 * 2;   // 12.8 MB
  w = (char*)(((uintptr_t)w + 255) & ~(uintptr_t)255);
  char* regionB = w;           w += (size_t)E * 8;        // 12.8 MB
  w = (char*)(((uintptr_t)w + 255) & ~(uintptr_t)255);
  char* regionC = w;           w += (size_t)N * 128 * 2;  // 25.6 MB

  int* M = (int*)regionA;                 // 0.4 MB
  int* bsum = M + MLEN;                   // 2 KB
  int* edata2 = bsum + 512;               // EN*4 = 6.8 MB (tot 7.3 <= 12.8)
  __half* ht1 = (__half*)regionA;         // after edge_weight
  int2* edata1 = (int2*)regionB;          // E*8 = 12.8 MB
  __half* a2 = (__half*)regionB;          // after bucket_sort, N*64*2
  __half* hout1 = (__half*)regionC;       // agg1 -> agg2
  __half* h2 = (__half*)regionC;          // gemm2 -> gemm3, N*128*2

  const int NBS = (MLEN + 255) / 256;  // 391 (<=512)
  const int NW = (N + 7) / 8;          // aggregation waves
  const int AGB = (NW + 3) / 4;        // aggregation blocks

  // ---- CSR build (with self-loops) ----
  bucket_hist_kernel<<<NWGA, 256, 0, stream>>>(ei + E, E, chunk, NBUK, M);
  scan_blocksum<<<NBS, 256, 0, stream>>>(M, MLEN, bsum);
  scan_bsums<<<1, 512, 0, stream>>>(bsum, NBS);
  scan_final<<<NBS, 256, 0, stream>>>(M, MLEN, bsum);
  bucket_scatter_kernel<<<NWGA, 256, 0, stream>>>(ei, E, chunk, NBUK, M, edata1);
  bucket_sort_kernel<<<NBUK, 256, 0, stream>>>(edata1, M, E, N, NBUK, offsets,
                                               dinv, edata2);
  edge_weight_kernel<<<1024, 256, 0, stream>>>(edata2, EN, edata3);

  // ---- Layer 1 ----
  gemm_kernel<128, 64, false, true, float, __half>
      <<<(N + 63) / 64, 256, 0, stream>>>(x, W1, nullptr, dinv, ht1, N);
  agg_kernel<true, true, true, __half><<<AGB, 256, 0, stream>>>(
      ht1, edata3, offsets, dinv, b1, hout1, N);

  // ---- Layer 2 ----
  agg_kernel<false, false, false, __half><<<AGB, 256, 0, stream>>>(
      hout1, edata3, offsets, dinv, nullptr, a2, N);
  gemm_kernel<64, 128, true, false, __half, __half>
      <<<(N + 31) / 32, 256, 0, stream>>>(a2, W2, b2, nullptr, h2, N);

  // ---- Layer 3 ----
  gemm_kernel<128, 64, false, true, __half, __half>
      <<<(N + 63) / 64, 256, 0, stream>>>(h2, W3, nullptr, dinv, ht1, N);
  agg_kernel<true, false, false, float><<<AGB, 256, 0, stream>>>(
      ht1, edata3, offsets, dinv, b3, (float*)d_out, N);
}

// Round 6
// 337.667 us; speedup vs baseline: 1.8662x; 1.1191x over previous
//
#include <hip/hip_runtime.h>
#include <hip/hip_fp16.h>
#include <stdint.h>

// ---------------------------------------------------------------------------
// GCN 3-layer forward on MI355X.
// CSR build (bucket sort) inserts SELF-LOOP edges; weights dinv[src] are
// pre-folded into fp16 gather tables by the producing GEMM/agg epilogue, so
// the edge stream is a 4B row-byte-offset. Aggregation: one wave per 8
// consecutive nodes = one contiguous edge run; edge indices pre-loaded
// lane-spread and broadcast via __shfl so the gather pipeline never drains.
// GEMMs: MFMA v_mfma_f32_16x16x32_f16, W^T in LDS (XOR-swizzled), fused
// dinv / bias+relu epilogues, fp16 outputs.
//   t1' = dinv*(x@W1) (fp16)   ; out1' = dinv*relu(dn*Agg(t1')+b1) (fp16)
//   a2  = dn*Agg(out1') (fp16) ; h2 = relu(a2@W2+b2) (fp16)
//   t3' = dinv*(h2@W3) (fp16)  ; out = dn*Agg(t3')+b3 (fp32)
// ---------------------------------------------------------------------------

#define NWGA 256  // workgroups for edge-chunk passes
#define CMAX 8    // max 64-edge chunks per wave (8 nodes, cap 512 edges)

typedef _Float16 half8 __attribute__((ext_vector_type(8)));
typedef float f32x4 __attribute__((ext_vector_type(4)));

struct __align__(8) Half4 { __half x, y, z, w; };

// ---- A1: per-wg bucket histogram ------------------------------------------
__global__ __launch_bounds__(256) void bucket_hist_kernel(
    const int* __restrict__ dst, int E, int chunk, int NBUK,
    int* __restrict__ M /* [NBUK][NWGA] */) {
  __shared__ int hist[512];
  const int w = blockIdx.x, t = threadIdx.x;
  for (int i = t; i < NBUK; i += 256) hist[i] = 0;
  __syncthreads();
  const int e0 = w * chunk;
  const int e1 = min(e0 + chunk, E);
  for (int e = e0 + t; e < e1; e += 256) atomicAdd(&hist[dst[e] >> 8], 1);
  __syncthreads();
  for (int i = t; i < NBUK; i += 256) M[i * NWGA + w] = hist[i];
}

// ---- scan helpers ---------------------------------------------------------
__global__ void scan_blocksum(const int* __restrict__ data, int len,
                              int* __restrict__ bsum) {
  __shared__ int s[256];
  int i = blockIdx.x * 256 + threadIdx.x;
  s[threadIdx.x] = (i < len) ? data[i] : 0;
  __syncthreads();
  for (int off = 128; off > 0; off >>= 1) {
    if (threadIdx.x < off) s[threadIdx.x] += s[threadIdx.x + off];
    __syncthreads();
  }
  if (threadIdx.x == 0) bsum[blockIdx.x] = s[0];
}

__global__ void scan_bsums(int* bsum, int NB) {
  __shared__ int s[512];
  int t = threadIdx.x;
  int v = (t < NB) ? bsum[t] : 0;
  s[t] = v;
  __syncthreads();
  for (int off = 1; off < 512; off <<= 1) {
    int u = (t >= off) ? s[t - off] : 0;
    __syncthreads();
    s[t] += u;
    __syncthreads();
  }
  if (t < NB) bsum[t] = s[t] - v;  // exclusive block base
}

__global__ void scan_final(int* __restrict__ data, int len,
                           const int* __restrict__ bsum) {
  __shared__ int s[256];
  int t = threadIdx.x;
  int i = blockIdx.x * 256 + t;
  int v = (i < len) ? data[i] : 0;
  s[t] = v;
  __syncthreads();
  for (int off = 1; off < 256; off <<= 1) {
    int u = (t >= off) ? s[t - off] : 0;
    __syncthreads();
    s[t] += u;
    __syncthreads();
  }
  if (i < len) data[i] = bsum[blockIdx.x] + s[t] - v;  // exclusive, in-place
}

// ---- A2: scatter edges into reserved contiguous bucket runs ---------------
__global__ __launch_bounds__(256) void bucket_scatter_kernel(
    const int* __restrict__ ei, int E, int chunk, int NBUK,
    const int* __restrict__ Mscan, int2* __restrict__ edata1) {
  __shared__ int cur[512];
  const int w = blockIdx.x, t = threadIdx.x;
  for (int i = t; i < NBUK; i += 256) cur[i] = Mscan[i * NWGA + w];
  __syncthreads();
  const int e0 = w * chunk;
  const int e1 = min(e0 + chunk, E);
  for (int e = e0 + t; e < e1; e += 256) {
    int s = ei[e];
    int d = ei[E + e];
    int pos = atomicAdd(&cur[d >> 8], 1);
    edata1[pos] = make_int2(s, d);
  }
}

// ---- B: per-bucket counting sort; inserts self-loop as FIRST edge ---------
__global__ __launch_bounds__(256) void bucket_sort_kernel(
    const int2* __restrict__ edata1, const int* __restrict__ Mscan, int E,
    int N, int NBUK, int* __restrict__ offsets, float* __restrict__ dinv,
    int* __restrict__ edata2) {
  __shared__ int hist[256];
  __shared__ int cursor[256];
  const int b = blockIdx.x, t = threadIdx.x;
  const int ebase = Mscan[b * NWGA];
  const int eend = (b + 1 < NBUK) ? Mscan[(b + 1) * NWGA] : E;
  const int nodebase = b << 8;
  const int node = nodebase + t;
  const int base = ebase + min(nodebase, N);  // + prior buckets' self-loops
  hist[t] = (node < N) ? 1 : 0;               // self-loop
  __syncthreads();
  for (int e = ebase + t; e < eend; e += 256)
    atomicAdd(&hist[edata1[e].y - nodebase], 1);
  __syncthreads();
  const int deg = hist[t];  // edges + self
  for (int off = 1; off < 256; off <<= 1) {  // inclusive scan
    int u = (t >= off) ? hist[t - off] : 0;
    __syncthreads();
    hist[t] += u;
    __syncthreads();
  }
  const int excl = hist[t] - deg;
  cursor[t] = base + excl + 1;  // slot 0 = self
  if (node < N) {
    offsets[node] = base + excl;
    dinv[node] = rsqrtf((float)deg);
    edata2[base + excl] = node;  // self edge
  }
  if (node == N - 1) offsets[N] = E + N;
  __syncthreads();
  for (int e = ebase + t; e < eend; e += 256) {
    int2 sd = edata1[e];
    int pos = atomicAdd(&cursor[sd.y - nodebase], 1);
    edata2[pos] = sd.x;
  }
}

// ---- C: per-edge row byte-offset (table rows are 128B fp16) ---------------
__global__ __launch_bounds__(256) void edge_weight_kernel(
    const int* __restrict__ edata2, int EN, int* __restrict__ ed3) {
  int stride = gridDim.x * blockDim.x;
  for (int e = blockIdx.x * blockDim.x + threadIdx.x; e < EN; e += stride)
    ed3[e] = edata2[e] << 7;
}

// ---- MFMA GEMM: H[N,D] = X[N,K]@W[K,D] (+bias,relu / *dinv[row]), fp16 out
// Block: 256 thr = 4 waves; wave = 32 rows (2 row-tiles of 16); block = 128.
// W^T staged in LDS [D][K] fp16 with 16B-chunk XOR swizzle (chunk ^= d&7).
// Frags (16x16x32): A row=l&15,k=(l>>4)*8+j ; B col=l&15 same k ;
//                   C/D col=l&15,row=(l>>4)*4+reg.
template <int K, int D, bool BR, bool DSCALE, typename InT>
__global__ __launch_bounds__(256) void gemm_mfma(
    const InT* __restrict__ X, const float* __restrict__ W,
    const float* __restrict__ bias, const float* __restrict__ dinv,
    _Float16* __restrict__ H, int N) {
  __shared__ char lds[2 * K * D];
  const int t = threadIdx.x;
  // stage W^T (swizzled). consecutive t -> consecutive k, same d:
  // LDS writes conflict-free; global reads strided but W is 32KB L2-hot.
  for (int idx = t; idx < K * D; idx += 256) {
    const int k = idx % K;
    const int d = idx / K;
    const _Float16 v = (_Float16)W[k * D + d];
    const int byte =
        d * (2 * K) + ((((k >> 3) ^ (d & 7)) << 4) | ((k & 7) << 1));
    *(_Float16*)(lds + byte) = v;
  }
  __syncthreads();

  const int w = t >> 6;
  const int l = t & 63;
  const int lrow = l & 15;
  const int lg = l >> 4;
  const int r0 = blockIdx.x * 128 + w * 32;
  if (r0 >= N) return;

  f32x4 acc[2][D / 16];
#pragma unroll
  for (int rt = 0; rt < 2; ++rt)
#pragma unroll
    for (int c = 0; c < D / 16; ++c) acc[rt][c] = (f32x4){0.f, 0.f, 0.f, 0.f};

  int rA[2];
  rA[0] = min(r0 + lrow, N - 1);
  rA[1] = min(r0 + 16 + lrow, N - 1);

#pragma unroll
  for (int s = 0; s < K / 32; ++s) {
    half8 a[2];
#pragma unroll
    for (int rt = 0; rt < 2; ++rt) {
      if constexpr (sizeof(InT) == 2) {
        a[rt] = *reinterpret_cast<const half8*>(
            (const _Float16*)X + (size_t)rA[rt] * K + s * 32 + lg * 8);
      } else {
        const float* xp = (const float*)X + (size_t)rA[rt] * K + s * 32 + lg * 8;
        float4 lo = *reinterpret_cast<const float4*>(xp);
        float4 hi = *reinterpret_cast<const float4*>(xp + 4);
        half8 af;
        af[0] = (_Float16)lo.x; af[1] = (_Float16)lo.y;
        af[2] = (_Float16)lo.z; af[3] = (_Float16)lo.w;
        af[4] = (_Float16)hi.x; af[5] = (_Float16)hi.y;
        af[6] = (_Float16)hi.z; af[7] = (_Float16)hi.w;
        a[rt] = af;
      }
    }
    half8 b[D / 16];
#pragma unroll
    for (int c = 0; c < D / 16; ++c) {
      const int d = c * 16 + lrow;
      const int g = s * 4 + lg;
      b[c] = *reinterpret_cast<const half8*>(
          lds + d * (2 * K) + (((g ^ (d & 7)) << 4)));
    }
#pragma unroll
    for (int rt = 0; rt < 2; ++rt)
#pragma unroll
      for (int c = 0; c < D / 16; ++c)
        acc[rt][c] = __builtin_amdgcn_mfma_f32_16x16x32_f16(a[rt], b[c],
                                                            acc[rt][c], 0, 0, 0);
  }

  // epilogue
  float bv[D / 16];
  if (BR) {
#pragma unroll
    for (int c = 0; c < D / 16; ++c) bv[c] = bias[c * 16 + lrow];
  }
#pragma unroll
  for (int rt = 0; rt < 2; ++rt) {
#pragma unroll
    for (int r = 0; r < 4; ++r) {
      const int row = r0 + rt * 16 + lg * 4 + r;
      if (row < N) {
        float ds = 1.f;
        if (DSCALE) ds = dinv[row];
#pragma unroll
        for (int c = 0; c < D / 16; ++c) {
          float v = acc[rt][c][r];
          if (BR) v = fmaxf(v + bv[c], 0.f);
          if (DSCALE) v *= ds;
          H[(size_t)row * D + c * 16 + lrow] = (_Float16)v;
        }
      }
    }
  }
}

// ---- Aggregation: wave = 8 consecutive nodes = 1 contiguous edge run ------
template <bool BIAS, bool RELU, bool SCALE_OUT, typename OutT>
__global__ __launch_bounds__(256) void agg_kernel(
    const __half* __restrict__ h, const int* __restrict__ ed,
    const int* __restrict__ offsets, const float* __restrict__ dinv,
    const float* __restrict__ bias, OutT* __restrict__ out, int N) {
  const int wid = blockIdx.x * 4 + (threadIdx.x >> 6);
  const int na = wid * 8;
  if (na >= N) return;
  const int lane = threadIdx.x & 63;
  const int nrem = min(8, N - na);

  const int off_l = offsets[na + min(lane, nrem)];
  const float dn_l = dinv[na + min(lane, nrem - 1)];
  const int eb0 = __shfl(off_l, 0);
  const int eb1 = __shfl(off_l, nrem);
  float bsv = 0.f;
  if (BIAS) bsv = bias[lane];

  int pe[CMAX];
#pragma unroll
  for (int c = 0; c < CMAX; ++c) {
    int idx = eb0 + c * 64 + lane;
    pe[c] = ed[min(idx, eb1 - 1)];
  }

  const char* hb = (const char*)h;
  float acc = 0.f;
  int cur = 0;
  int bnd = __shfl(off_l, 1);
  float dn = __shfl(dn_l, 0);
  int j = eb0;

#define FLUSH()                                                        \
  {                                                                    \
    float v = acc * dn;                                                \
    if (BIAS) v += bsv;                                                \
    if (RELU) v = fmaxf(v, 0.f);                                       \
    if (SCALE_OUT) v *= dn;                                            \
    if constexpr (sizeof(OutT) == 2)                                   \
      out[(size_t)(na + cur) * 64 + lane] = __float2half(v);           \
    else                                                               \
      out[(size_t)(na + cur) * 64 + lane] = v;                         \
    acc = 0.f;                                                         \
    cur++;                                                             \
    bnd = __shfl(off_l, min(cur + 1, 8));                              \
    dn = __shfl(dn_l, min(cur, 7));                                    \
  }

#pragma unroll
  for (int c = 0; c < CMAX; ++c) {
    if (j < eb1) {
      const int pc = pe[c];  // static index
      for (int k = 0; k < 64; k += 8) {
        if (j >= eb1) break;
        int so[8];
        float g[8], wv[8];
#pragma unroll
        for (int i = 0; i < 8; ++i) {
          so[i] = __shfl(pc, k + i);
          wv[i] = (j + i < eb1) ? 1.f : 0.f;
        }
#pragma unroll
        for (int i = 0; i < 8; ++i)
          g[i] = __half2float(
              *(const __half*)(hb + (size_t)(unsigned)so[i] + lane * 2));
#pragma unroll
        for (int i = 0; i < 8; ++i) {
          if (j + i == bnd) FLUSH();
          acc = fmaf(g[i], wv[i], acc);
        }
        j += 8;
      }
    }
  }
  for (; j < eb1; ++j) {
    int so = ed[j];
    float g =
        __half2float(*(const __half*)(hb + (size_t)(unsigned)so + lane * 2));
    if (j == bnd) FLUSH();
    acc += g;
  }
  if (cur < nrem) FLUSH();
#undef FLUSH
}

extern "C" void kernel_launch(void* const* d_in, const int* in_sizes, int n_in,
                              void* d_out, int out_size, void* d_ws,
                              size_t ws_size, hipStream_t stream) {
  const float* x  = (const float*)d_in[0];
  const int*   ei = (const int*)d_in[1];
  const float* W1 = (const float*)d_in[2];
  const float* b1 = (const float*)d_in[3];
  const float* W2 = (const float*)d_in[4];
  const float* b2 = (const float*)d_in[5];
  const float* W3 = (const float*)d_in[6];
  const float* b3 = (const float*)d_in[7];

  const int N = in_sizes[0] / 128;
  const int E = in_sizes[1] / 2;
  const int EN = E + N;
  const int NBUK = (N + 255) >> 8;          // 391 for N=100000
  const int MLEN = NBUK * NWGA;             // 100096
  const int chunk = (E + NWGA - 1) / NWGA;  // 6250

  // Workspace (~60 MB) with lifetime aliasing:
  char* w = (char*)d_ws;
  int* offsets = (int*)w;      w += (size_t)(N + 2) * 4;
  float* dinv = (float*)w;     w += (size_t)N * 4;
  w = (char*)(((uintptr_t)w + 255) & ~(uintptr_t)255);
  int* edata3 = (int*)w;       w += (size_t)EN * 4;
  w = (char*)(((uintptr_t)w + 255) & ~(uintptr_t)255);
  char* regionA = w;           w += (size_t)N * 64 * 2;   // 12.8 MB
  w = (char*)(((uintptr_t)w + 255) & ~(uintptr_t)255);
  char* regionB = w;           w += (size_t)E * 8;        // 12.8 MB
  w = (char*)(((uintptr_t)w + 255) & ~(uintptr_t)255);
  char* regionC = w;           w += (size_t)N * 128 * 2;  // 25.6 MB

  int* M = (int*)regionA;                 // 0.4 MB
  int* bsum = M + MLEN;                   // 2 KB
  int* edata2 = bsum + 512;               // EN*4 = 6.8 MB (tot 7.3 <= 12.8)
  _Float16* ht1 = (_Float16*)regionA;     // after edge_weight
  int2* edata1 = (int2*)regionB;          // E*8 = 12.8 MB
  _Float16* a2 = (_Float16*)regionB;      // after bucket_sort, N*64*2
  _Float16* hout1 = (_Float16*)regionC;   // agg1 -> agg2
  _Float16* h2 = (_Float16*)regionC;      // gemm2 -> gemm3, N*128*2

  const int NBS = (MLEN + 255) / 256;  // 391 (<=512)
  const int NW = (N + 7) / 8;          // aggregation waves
  const int AGB = (NW + 3) / 4;        // aggregation blocks
  const int GGB = (N + 127) / 128;     // gemm blocks

  // ---- CSR build (with self-loops) ----
  bucket_hist_kernel<<<NWGA, 256, 0, stream>>>(ei + E, E, chunk, NBUK, M);
  scan_blocksum<<<NBS, 256, 0, stream>>>(M, MLEN, bsum);
  scan_bsums<<<1, 512, 0, stream>>>(bsum, NBS);
  scan_final<<<NBS, 256, 0, stream>>>(M, MLEN, bsum);
  bucket_scatter_kernel<<<NWGA, 256, 0, stream>>>(ei, E, chunk, NBUK, M, edata1);
  bucket_sort_kernel<<<NBUK, 256, 0, stream>>>(edata1, M, E, N, NBUK, offsets,
                                               dinv, edata2);
  edge_weight_kernel<<<1024, 256, 0, stream>>>(edata2, EN, edata3);

  // ---- Layer 1 ----
  gemm_mfma<128, 64, false, true, float><<<GGB, 256, 0, stream>>>(
      x, W1, nullptr, dinv, ht1, N);
  agg_kernel<true, true, true, __half><<<AGB, 256, 0, stream>>>(
      (const __half*)ht1, edata3, offsets, dinv, b1, (__half*)hout1, N);

  // ---- Layer 2 ----
  agg_kernel<false, false, false, __half><<<AGB, 256, 0, stream>>>(
      (const __half*)hout1, edata3, offsets, dinv, nullptr, (__half*)a2, N);
  gemm_mfma<64, 128, true, false, _Float16><<<GGB, 256, 0, stream>>>(
      a2, W2, b2, nullptr, h2, N);

  // ---- Layer 3 ----
  gemm_mfma<128, 64, false, true, _Float16><<<GGB, 256, 0, stream>>>(
      h2, W3, nullptr, dinv, ht1, N);
  agg_kernel<true, false, false, float><<<AGB, 256, 0, stream>>>(
      (const __half*)ht1, edata3, offsets, dinv, b3, (float*)d_out, N);
}

// Round 7
// 323.382 us; speedup vs baseline: 1.9487x; 1.0442x over previous
//
#include <hip/hip_runtime.h>
#include <hip/hip_fp16.h>
#include <stdint.h>

// ---------------------------------------------------------------------------
// GCN 3-layer forward on MI355X.
// CSR build (bucket sort) inserts SELF-LOOP edges and PADS every node's edge
// run to even length with edges pointing at a reserved all-zero row (row N),
// so all CSR offsets are even. Weights dinv[src] are pre-folded into fp16
// gather tables; the edge stream is a pre-shifted 4B row-byte-offset.
// Aggregation: one wave per 8 consecutive nodes = one contiguous edge run;
// PAIR-GATHER: each lane loads __half2 (2 features), 32 lanes cover a row,
// one wave-load gathers TWO edges (lo half = even edge, hi half = odd edge);
// halves combined with one shfl_xor(32) at node flush.
// GEMMs: MFMA v_mfma_f32_16x16x32_f16, W^T in LDS (XOR-swizzled), fused
// dinv / bias+relu epilogues, fp16 outputs.
//   t1' = dinv*(x@W1) (fp16)   ; out1' = dinv*relu(dn*Agg(t1')+b1) (fp16)
//   a2  = dn*Agg(out1') (fp16) ; h2 = relu(a2@W2+b2) (fp16)
//   t3' = dinv*(h2@W3) (fp16)  ; out = dn*Agg(t3')+b3 (fp32)
// ---------------------------------------------------------------------------

#define NWGA 256  // workgroups for edge-chunk passes
#define CMAX 8    // max 64-edge chunks per wave (8 nodes, cap 512 edges)

typedef _Float16 half8 __attribute__((ext_vector_type(8)));
typedef float f32x4 __attribute__((ext_vector_type(4)));

struct __align__(8) Half4 { __half x, y, z, w; };

// ---- A1: per-wg bucket histogram ------------------------------------------
__global__ __launch_bounds__(256) void bucket_hist_kernel(
    const int* __restrict__ dst, int E, int chunk, int NBUK,
    int* __restrict__ M /* [NBUK][NWGA] */) {
  __shared__ int hist[512];
  const int w = blockIdx.x, t = threadIdx.x;
  for (int i = t; i < NBUK; i += 256) hist[i] = 0;
  __syncthreads();
  const int e0 = w * chunk;
  const int e1 = min(e0 + chunk, E);
  for (int e = e0 + t; e < e1; e += 256) atomicAdd(&hist[dst[e] >> 8], 1);
  __syncthreads();
  for (int i = t; i < NBUK; i += 256) M[i * NWGA + w] = hist[i];
}

// ---- scan helpers (for the M matrix) --------------------------------------
__global__ void scan_blocksum(const int* __restrict__ data, int len,
                              int* __restrict__ bsum) {
  __shared__ int s[256];
  int i = blockIdx.x * 256 + threadIdx.x;
  s[threadIdx.x] = (i < len) ? data[i] : 0;
  __syncthreads();
  for (int off = 128; off > 0; off >>= 1) {
    if (threadIdx.x < off) s[threadIdx.x] += s[threadIdx.x + off];
    __syncthreads();
  }
  if (threadIdx.x == 0) bsum[blockIdx.x] = s[0];
}

__global__ void scan_bsums(int* bsum, int NB) {
  __shared__ int s[512];
  int t = threadIdx.x;
  int v = (t < NB) ? bsum[t] : 0;
  s[t] = v;
  __syncthreads();
  for (int off = 1; off < 512; off <<= 1) {
    int u = (t >= off) ? s[t - off] : 0;
    __syncthreads();
    s[t] += u;
    __syncthreads();
  }
  if (t < NB) bsum[t] = s[t] - v;  // exclusive block base
}

__global__ void scan_final(int* __restrict__ data, int len,
                           const int* __restrict__ bsum) {
  __shared__ int s[256];
  int t = threadIdx.x;
  int i = blockIdx.x * 256 + t;
  int v = (i < len) ? data[i] : 0;
  s[t] = v;
  __syncthreads();
  for (int off = 1; off < 256; off <<= 1) {
    int u = (t >= off) ? s[t - off] : 0;
    __syncthreads();
    s[t] += u;
    __syncthreads();
  }
  if (i < len) data[i] = bsum[blockIdx.x] + s[t] - v;  // exclusive, in-place
}

// ---- A2: scatter edges into reserved contiguous bucket runs ---------------
__global__ __launch_bounds__(256) void bucket_scatter_kernel(
    const int* __restrict__ ei, int E, int chunk, int NBUK,
    const int* __restrict__ Mscan, int2* __restrict__ edata1) {
  __shared__ int cur[512];
  const int w = blockIdx.x, t = threadIdx.x;
  for (int i = t; i < NBUK; i += 256) cur[i] = Mscan[i * NWGA + w];
  __syncthreads();
  const int e0 = w * chunk;
  const int e1 = min(e0 + chunk, E);
  for (int e = e0 + t; e < e1; e += 256) {
    int s = ei[e];
    int d = ei[E + e];
    int pos = atomicAdd(&cur[d >> 8], 1);
    edata1[pos] = make_int2(s, d);
  }
}

// ---- B1: per-bucket degrees, dinv, per-bucket padded totals ---------------
__global__ __launch_bounds__(256) void bucket_deg_kernel(
    const int2* __restrict__ edata1, const int* __restrict__ Mscan, int E,
    int N, int NBUK, int* __restrict__ deg_arr, float* __restrict__ dinv,
    int* __restrict__ bsum2) {
  __shared__ int hist[256];
  __shared__ int red[256];
  const int b = blockIdx.x, t = threadIdx.x;
  const int ebase = Mscan[b * NWGA];
  const int eend = (b + 1 < NBUK) ? Mscan[(b + 1) * NWGA] : E;
  const int nodebase = b << 8;
  const int node = nodebase + t;
  hist[t] = 0;
  __syncthreads();
  for (int e = ebase + t; e < eend; e += 256)
    atomicAdd(&hist[edata1[e].y - nodebase], 1);
  __syncthreads();
  int pd = 0;
  if (node < N) {
    int dt = hist[t] + 1;  // + self-loop
    pd = dt + (dt & 1);    // pad to even
    deg_arr[node] = dt;
    dinv[node] = rsqrtf((float)dt);
  }
  red[t] = pd;
  __syncthreads();
  for (int off = 128; off > 0; off >>= 1) {
    if (t < off) red[t] += red[t + off];
    __syncthreads();
  }
  if (t == 0) bsum2[b] = red[0];
}

// ---- bucket-base scan (NBUK <= 512) ---------------------------------------
__global__ void bucket_base_scan(int* bsum2, int NBUK, int* offsets, int N) {
  __shared__ int s[512];
  int t = threadIdx.x;
  int v = (t < NBUK) ? bsum2[t] : 0;
  s[t] = v;
  __syncthreads();
  for (int off = 1; off < 512; off <<= 1) {
    int u = (t >= off) ? s[t - off] : 0;
    __syncthreads();
    s[t] += u;
    __syncthreads();
  }
  if (t < NBUK) bsum2[t] = s[t] - v;     // exclusive base
  if (t == NBUK - 1) offsets[N] = s[t];  // EP = total padded edges
}

// ---- B2: offsets + scatter pre-shifted byte offsets (self first, pad) -----
__global__ __launch_bounds__(256) void bucket_fill_kernel(
    const int2* __restrict__ edata1, const int* __restrict__ Mscan,
    const int* __restrict__ deg_arr, const int* __restrict__ bsum2, int E,
    int N, int NBUK, int* __restrict__ offsets, int* __restrict__ ed3) {
  __shared__ int scan[256];
  __shared__ int cursor[256];
  const int b = blockIdx.x, t = threadIdx.x;
  const int ebase = Mscan[b * NWGA];
  const int eend = (b + 1 < NBUK) ? Mscan[(b + 1) * NWGA] : E;
  const int nodebase = b << 8;
  const int node = nodebase + t;
  const int dt = (node < N) ? deg_arr[node] : 0;
  const int pd = dt + (dt & 1);
  scan[t] = pd;
  __syncthreads();
  for (int off = 1; off < 256; off <<= 1) {
    int u = (t >= off) ? scan[t - off] : 0;
    __syncthreads();
    scan[t] += u;
    __syncthreads();
  }
  const int base = bsum2[b] + scan[t] - pd;
  cursor[t] = base + 1;  // slot 0 = self
  if (node < N) {
    offsets[node] = base;
    ed3[base] = node << 7;                // self edge (byte offset)
    if (dt & 1) ed3[base + dt] = N << 7;  // pad -> zero row
  }
  __syncthreads();
  for (int e = ebase + t; e < eend; e += 256) {
    int2 sd = edata1[e];
    int pos = atomicAdd(&cursor[sd.y - nodebase], 1);
    ed3[pos] = sd.x << 7;
  }
}

// ---- zero rows (row N of the two agg input tables) ------------------------
__global__ void zero_rows_kernel(_Float16* a, _Float16* b) {
  if (threadIdx.x < 64) a[threadIdx.x] = (_Float16)0.f;
  else b[threadIdx.x - 64] = (_Float16)0.f;
}

// ---- MFMA GEMM: H[N,D] = X[N,K]@W[K,D] (+bias,relu / *dinv[row]), fp16 out
template <int K, int D, bool BR, bool DSCALE, typename InT>
__global__ __launch_bounds__(256) void gemm_mfma(
    const InT* __restrict__ X, const float* __restrict__ W,
    const float* __restrict__ bias, const float* __restrict__ dinv,
    _Float16* __restrict__ H, int N) {
  __shared__ char lds[2 * K * D];
  const int t = threadIdx.x;
  for (int idx = t; idx < K * D; idx += 256) {
    const int k = idx % K;
    const int d = idx / K;
    const _Float16 v = (_Float16)W[k * D + d];
    const int byte =
        d * (2 * K) + ((((k >> 3) ^ (d & 7)) << 4) | ((k & 7) << 1));
    *(_Float16*)(lds + byte) = v;
  }
  __syncthreads();

  const int w = t >> 6;
  const int l = t & 63;
  const int lrow = l & 15;
  const int lg = l >> 4;
  const int r0 = blockIdx.x * 128 + w * 32;
  if (r0 >= N) return;

  f32x4 acc[2][D / 16];
#pragma unroll
  for (int rt = 0; rt < 2; ++rt)
#pragma unroll
    for (int c = 0; c < D / 16; ++c) acc[rt][c] = (f32x4){0.f, 0.f, 0.f, 0.f};

  int rA[2];
  rA[0] = min(r0 + lrow, N - 1);
  rA[1] = min(r0 + 16 + lrow, N - 1);

#pragma unroll
  for (int s = 0; s < K / 32; ++s) {
    half8 a[2];
#pragma unroll
    for (int rt = 0; rt < 2; ++rt) {
      if constexpr (sizeof(InT) == 2) {
        a[rt] = *reinterpret_cast<const half8*>(
            (const _Float16*)X + (size_t)rA[rt] * K + s * 32 + lg * 8);
      } else {
        const float* xp = (const float*)X + (size_t)rA[rt] * K + s * 32 + lg * 8;
        float4 lo = *reinterpret_cast<const float4*>(xp);
        float4 hi = *reinterpret_cast<const float4*>(xp + 4);
        half8 af;
        af[0] = (_Float16)lo.x; af[1] = (_Float16)lo.y;
        af[2] = (_Float16)lo.z; af[3] = (_Float16)lo.w;
        af[4] = (_Float16)hi.x; af[5] = (_Float16)hi.y;
        af[6] = (_Float16)hi.z; af[7] = (_Float16)hi.w;
        a[rt] = af;
      }
    }
    half8 b[D / 16];
#pragma unroll
    for (int c = 0; c < D / 16; ++c) {
      const int d = c * 16 + lrow;
      const int g = s * 4 + lg;
      b[c] = *reinterpret_cast<const half8*>(
          lds + d * (2 * K) + (((g ^ (d & 7)) << 4)));
    }
#pragma unroll
    for (int rt = 0; rt < 2; ++rt)
#pragma unroll
      for (int c = 0; c < D / 16; ++c)
        acc[rt][c] = __builtin_amdgcn_mfma_f32_16x16x32_f16(a[rt], b[c],
                                                            acc[rt][c], 0, 0, 0);
  }

  float bv[D / 16];
  if (BR) {
#pragma unroll
    for (int c = 0; c < D / 16; ++c) bv[c] = bias[c * 16 + lrow];
  }
#pragma unroll
  for (int rt = 0; rt < 2; ++rt) {
#pragma unroll
    for (int r = 0; r < 4; ++r) {
      const int row = r0 + rt * 16 + lg * 4 + r;
      if (row < N) {
        float ds = 1.f;
        if (DSCALE) ds = dinv[row];
#pragma unroll
        for (int c = 0; c < D / 16; ++c) {
          float v = acc[rt][c][r];
          if (BR) v = fmaxf(v + bv[c], 0.f);
          if (DSCALE) v *= ds;
          H[(size_t)row * D + c * 16 + lrow] = (_Float16)v;
        }
      }
    }
  }
}

// ---- Aggregation: wave = 8 nodes, pair-gather (2 edges / wave-load) -------
template <bool BIAS, bool RELU, bool SCALE_OUT, typename OutT>
__global__ __launch_bounds__(256) void agg_kernel(
    const __half* __restrict__ h, const int* __restrict__ ed,
    const int* __restrict__ offsets, const float* __restrict__ dinv,
    const float* __restrict__ bias, OutT* __restrict__ out, int N) {
  const int wid = blockIdx.x * 4 + (threadIdx.x >> 6);
  const int na = wid * 8;
  if (na >= N) return;
  const int lane = threadIdx.x & 63;
  const int half32 = lane >> 5;  // 0: even edge of pair, 1: odd edge
  const int fpair = lane & 31;   // feature pair (2f, 2f+1)
  const int nrem = min(8, N - na);

  const int off_l = offsets[na + min(lane, nrem)];
  const float dn_l = dinv[na + min(lane, nrem - 1)];
  const int eb0 = __shfl(off_l, 0);   // even
  const int eb1 = __shfl(off_l, nrem);
  float2 bsv = make_float2(0.f, 0.f);
  if (BIAS) bsv = *reinterpret_cast<const float2*>(&bias[fpair * 2]);

  // pre-issue ALL edge-offset loads, lane-spread (coalesced 256B each)
  int pe[CMAX];
#pragma unroll
  for (int c = 0; c < CMAX; ++c) {
    int idx = eb0 + c * 64 + lane;
    pe[c] = ed[min(idx, eb1 - 1)];
  }

  const char* hb = (const char*)h + (fpair << 2);
  float ax = 0.f, ay = 0.f;
  int cur = 0;
  int bnd = __shfl(off_l, 1);
  float dn = __shfl(dn_l, 0);
  int j = eb0;

  auto flush = [&]() {
    float tx = ax + __shfl_xor(ax, 32);
    float ty = ay + __shfl_xor(ay, 32);
    float vx = tx * dn, vy = ty * dn;
    if (BIAS) { vx += bsv.x; vy += bsv.y; }
    if (RELU) { vx = fmaxf(vx, 0.f); vy = fmaxf(vy, 0.f); }
    if (SCALE_OUT) { vx *= dn; vy *= dn; }
    if (lane < 32) {
      if constexpr (sizeof(OutT) == 2) {
        *reinterpret_cast<__half2*>((char*)out + ((size_t)(na + cur) << 7) +
                                    (fpair << 2)) = __floats2half2_rn(vx, vy);
      } else {
        *reinterpret_cast<float2*>((char*)out + ((size_t)(na + cur) << 8) +
                                   (fpair << 3)) = make_float2(vx, vy);
      }
    }
    ax = 0.f; ay = 0.f;
    cur++;
    bnd = __shfl(off_l, min(cur + 1, 8));
    dn = __shfl(dn_l, min(cur, 7));
  };

#pragma unroll
  for (int c = 0; c < CMAX; ++c) {
    if (j < eb1) {
      const int pc = pe[c];  // static index
      for (int kp = 0; kp < 64; kp += 8) {  // 4 pairs = 8 edges per iter
        if (j >= eb1) break;
        int so[4];
        float2 g[4];
#pragma unroll
        for (int i = 0; i < 4; ++i)
          so[i] = __shfl(pc, kp + 2 * i + half32);
#pragma unroll
        for (int i = 0; i < 4; ++i)
          g[i] = __half22float2(*reinterpret_cast<const __half2*>(
              hb + (size_t)(unsigned)so[i]));
#pragma unroll
        for (int i = 0; i < 4; ++i) {
          if (j + 2 * i == bnd) flush();
          ax += g[i].x;
          ay += g[i].y;
        }
        j += 8;
      }
    }
  }
  // fallback for runs > CMAX*64 edges (pair mode, direct loads)
  for (; j < eb1; j += 2) {
    int so = ed[j + half32];
    float2 g = __half22float2(
        *reinterpret_cast<const __half2*>(hb + (size_t)(unsigned)so));
    if (j == bnd) flush();
    ax += g.x;
    ay += g.y;
  }
  if (cur < nrem) flush();
}

extern "C" void kernel_launch(void* const* d_in, const int* in_sizes, int n_in,
                              void* d_out, int out_size, void* d_ws,
                              size_t ws_size, hipStream_t stream) {
  const float* x  = (const float*)d_in[0];
  const int*   ei = (const int*)d_in[1];
  const float* W1 = (const float*)d_in[2];
  const float* b1 = (const float*)d_in[3];
  const float* W2 = (const float*)d_in[4];
  const float* b2 = (const float*)d_in[5];
  const float* W3 = (const float*)d_in[6];
  const float* b3 = (const float*)d_in[7];

  const int N = in_sizes[0] / 128;
  const int E = in_sizes[1] / 2;
  const int NBUK = (N + 255) >> 8;          // 391 for N=100000
  const int MLEN = NBUK * NWGA;             // 100096
  const int chunk = (E + NWGA - 1) / NWGA;  // 6250

  // Workspace (~60 MB) with lifetime aliasing:
  //  perm   : offsets, dinv, deg, bsum2, edata3 (padded, E+2N)
  //  regionA: {M, bsum}(build)   -> ht1 ((N+1) x 64 fp16; row N = zeros)
  //  regionB: edata1(build)      -> a2  (N x 64 fp16)
  //  regionC: hout1 ((N+1) rows) -> h2  (N x 128 fp16)
  char* w = (char*)d_ws;
  int* offsets = (int*)w;      w += (size_t)(N + 2) * 4;
  float* dinv = (float*)w;     w += (size_t)N * 4;
  int* deg_arr = (int*)w;      w += (size_t)N * 4;
  int* bsum2 = (int*)w;        w += 512 * 4;
  w = (char*)(((uintptr_t)w + 255) & ~(uintptr_t)255);
  int* edata3 = (int*)w;       w += (size_t)(E + 2 * N) * 4;
  w = (char*)(((uintptr_t)w + 255) & ~(uintptr_t)255);
  char* regionA = w;           w += (size_t)(N + 1) * 64 * 2;
  w = (char*)(((uintptr_t)w + 255) & ~(uintptr_t)255);
  char* regionB = w;           w += (size_t)E * 8;
  w = (char*)(((uintptr_t)w + 255) & ~(uintptr_t)255);
  char* regionC = w;           w += (size_t)N * 128 * 2;

  int* M = (int*)regionA;                 // 0.4 MB (dead before ht1 row N use? no overlap: row N at 12.8MB)
  int* bsum = M + MLEN;                   // 2 KB
  _Float16* ht1 = (_Float16*)regionA;     // gemm1/3 out, agg1/3 in
  int2* edata1 = (int2*)regionB;          // E*8 = 12.8 MB
  _Float16* a2 = (_Float16*)regionB;      // after build, N*64*2
  _Float16* hout1 = (_Float16*)regionC;   // agg1 -> agg2 ((N+1) rows)
  _Float16* h2 = (_Float16*)regionC;      // gemm2 -> gemm3, N*128*2

  const int NBS = (MLEN + 255) / 256;  // 391 (<=512)
  const int NW = (N + 7) / 8;          // aggregation waves
  const int AGB = (NW + 3) / 4;        // aggregation blocks
  const int GGB = (N + 127) / 128;     // gemm blocks

  // ---- CSR build (self-loops + even padding; pre-shifted edge stream) ----
  zero_rows_kernel<<<1, 128, 0, stream>>>(ht1 + (size_t)N * 64,
                                          hout1 + (size_t)N * 64);
  bucket_hist_kernel<<<NWGA, 256, 0, stream>>>(ei + E, E, chunk, NBUK, M);
  scan_blocksum<<<NBS, 256, 0, stream>>>(M, MLEN, bsum);
  scan_bsums<<<1, 512, 0, stream>>>(bsum, NBS);
  scan_final<<<NBS, 256, 0, stream>>>(M, MLEN, bsum);
  bucket_scatter_kernel<<<NWGA, 256, 0, stream>>>(ei, E, chunk, NBUK, M, edata1);
  bucket_deg_kernel<<<NBUK, 256, 0, stream>>>(edata1, M, E, N, NBUK, deg_arr,
                                              dinv, bsum2);
  bucket_base_scan<<<1, 512, 0, stream>>>(bsum2, NBUK, offsets, N);
  bucket_fill_kernel<<<NBUK, 256, 0, stream>>>(edata1, M, deg_arr, bsum2, E, N,
                                               NBUK, offsets, edata3);

  // ---- Layer 1 ----
  gemm_mfma<128, 64, false, true, float><<<GGB, 256, 0, stream>>>(
      x, W1, nullptr, dinv, ht1, N);
  agg_kernel<true, true, true, __half><<<AGB, 256, 0, stream>>>(
      (const __half*)ht1, edata3, offsets, dinv, b1, (__half*)hout1, N);

  // ---- Layer 2 ----
  agg_kernel<false, false, false, __half><<<AGB, 256, 0, stream>>>(
      (const __half*)hout1, edata3, offsets, dinv, nullptr, (__half*)a2, N);
  gemm_mfma<64, 128, true, false, _Float16><<<GGB, 256, 0, stream>>>(
      a2, W2, b2, nullptr, h2, N);

  // ---- Layer 3 ----
  gemm_mfma<128, 64, false, true, _Float16><<<GGB, 256, 0, stream>>>(
      h2, W3, nullptr, dinv, ht1, N);
  agg_kernel<true, false, false, float><<<AGB, 256, 0, stream>>>(
      (const __half*)ht1, edata3, offsets, dinv, b3, (float*)d_out, N);
}

// Round 8
// 319.708 us; speedup vs baseline: 1.9711x; 1.0115x over previous
//
#include <hip/hip_runtime.h>
#include <hip/hip_fp16.h>
#include <stdint.h>

// ---------------------------------------------------------------------------
// GCN 3-layer forward on MI355X.
// CSR build (bucket sort) inserts SELF-LOOP edges and PADS every node's edge
// run to a MULTIPLE OF 4 with edges pointing at a reserved all-zero row
// (row N), so all CSR offsets are multiples of 4. Weights dinv[src] are
// pre-folded into fp16 gather tables; the edge stream is a pre-shifted 4B
// row-byte-offset. Aggregation: one wave per 8 consecutive nodes = one
// contiguous edge run; QUAD-GATHER: each lane loads half4 (4 features),
// 16 lanes cover a row, one wave-load gathers FOUR edges (lane-group g =
// edge g of the quad); groups combined with shfl_xor(16/32) at node flush.
// GEMMs: MFMA v_mfma_f32_16x16x32_f16, W^T in LDS (XOR-swizzled), fused
// dinv / bias+relu epilogues, fp16 outputs.
//   t1' = dinv*(x@W1) (fp16)   ; out1' = dinv*relu(dn*Agg(t1')+b1) (fp16)
//   a2  = dn*Agg(out1') (fp16) ; h2 = relu(a2@W2+b2) (fp16)
//   t3' = dinv*(h2@W3) (fp16)  ; out = dn*Agg(t3')+b3 (fp32)
// ---------------------------------------------------------------------------

#define NWGA 256  // workgroups for edge-chunk passes
#define CMAX 8    // max 64-edge chunks per wave (8 nodes, cap 512 edges)

typedef _Float16 half8 __attribute__((ext_vector_type(8)));
typedef float f32x4 __attribute__((ext_vector_type(4)));

struct __align__(8) Half4 { __half x, y, z, w; };

// ---- A1: per-wg bucket histogram ------------------------------------------
__global__ __launch_bounds__(256) void bucket_hist_kernel(
    const int* __restrict__ dst, int E, int chunk, int NBUK,
    int* __restrict__ M /* [NBUK][NWGA] */) {
  __shared__ int hist[512];
  const int w = blockIdx.x, t = threadIdx.x;
  for (int i = t; i < NBUK; i += 256) hist[i] = 0;
  __syncthreads();
  const int e0 = w * chunk;
  const int e1 = min(e0 + chunk, E);
  for (int e = e0 + t; e < e1; e += 256) atomicAdd(&hist[dst[e] >> 8], 1);
  __syncthreads();
  for (int i = t; i < NBUK; i += 256) M[i * NWGA + w] = hist[i];
}

// ---- scan helpers (for the M matrix) --------------------------------------
__global__ void scan_blocksum(const int* __restrict__ data, int len,
                              int* __restrict__ bsum) {
  __shared__ int s[256];
  int i = blockIdx.x * 256 + threadIdx.x;
  s[threadIdx.x] = (i < len) ? data[i] : 0;
  __syncthreads();
  for (int off = 128; off > 0; off >>= 1) {
    if (threadIdx.x < off) s[threadIdx.x] += s[threadIdx.x + off];
    __syncthreads();
  }
  if (threadIdx.x == 0) bsum[blockIdx.x] = s[0];
}

__global__ void scan_bsums(int* bsum, int NB) {
  __shared__ int s[512];
  int t = threadIdx.x;
  int v = (t < NB) ? bsum[t] : 0;
  s[t] = v;
  __syncthreads();
  for (int off = 1; off < 512; off <<= 1) {
    int u = (t >= off) ? s[t - off] : 0;
    __syncthreads();
    s[t] += u;
    __syncthreads();
  }
  if (t < NB) bsum[t] = s[t] - v;  // exclusive block base
}

__global__ void scan_final(int* __restrict__ data, int len,
                           const int* __restrict__ bsum) {
  __shared__ int s[256];
  int t = threadIdx.x;
  int i = blockIdx.x * 256 + t;
  int v = (i < len) ? data[i] : 0;
  s[t] = v;
  __syncthreads();
  for (int off = 1; off < 256; off <<= 1) {
    int u = (t >= off) ? s[t - off] : 0;
    __syncthreads();
    s[t] += u;
    __syncthreads();
  }
  if (i < len) data[i] = bsum[blockIdx.x] + s[t] - v;  // exclusive, in-place
}

// ---- A2: scatter edges into reserved contiguous bucket runs ---------------
__global__ __launch_bounds__(256) void bucket_scatter_kernel(
    const int* __restrict__ ei, int E, int chunk, int NBUK,
    const int* __restrict__ Mscan, int2* __restrict__ edata1) {
  __shared__ int cur[512];
  const int w = blockIdx.x, t = threadIdx.x;
  for (int i = t; i < NBUK; i += 256) cur[i] = Mscan[i * NWGA + w];
  __syncthreads();
  const int e0 = w * chunk;
  const int e1 = min(e0 + chunk, E);
  for (int e = e0 + t; e < e1; e += 256) {
    int s = ei[e];
    int d = ei[E + e];
    int pos = atomicAdd(&cur[d >> 8], 1);
    edata1[pos] = make_int2(s, d);
  }
}

// ---- B1: per-bucket degrees, dinv, per-bucket padded totals ---------------
__global__ __launch_bounds__(256) void bucket_deg_kernel(
    const int2* __restrict__ edata1, const int* __restrict__ Mscan, int E,
    int N, int NBUK, int* __restrict__ deg_arr, float* __restrict__ dinv,
    int* __restrict__ bsum2) {
  __shared__ int hist[256];
  __shared__ int red[256];
  const int b = blockIdx.x, t = threadIdx.x;
  const int ebase = Mscan[b * NWGA];
  const int eend = (b + 1 < NBUK) ? Mscan[(b + 1) * NWGA] : E;
  const int nodebase = b << 8;
  const int node = nodebase + t;
  hist[t] = 0;
  __syncthreads();
  for (int e = ebase + t; e < eend; e += 256)
    atomicAdd(&hist[edata1[e].y - nodebase], 1);
  __syncthreads();
  int pd = 0;
  if (node < N) {
    int dt = hist[t] + 1;   // + self-loop
    pd = (dt + 3) & ~3;     // pad to multiple of 4
    deg_arr[node] = dt;
    dinv[node] = rsqrtf((float)dt);
  }
  red[t] = pd;
  __syncthreads();
  for (int off = 128; off > 0; off >>= 1) {
    if (t < off) red[t] += red[t + off];
    __syncthreads();
  }
  if (t == 0) bsum2[b] = red[0];
}

// ---- bucket-base scan (NBUK <= 512) ---------------------------------------
__global__ void bucket_base_scan(int* bsum2, int NBUK, int* offsets, int N) {
  __shared__ int s[512];
  int t = threadIdx.x;
  int v = (t < NBUK) ? bsum2[t] : 0;
  s[t] = v;
  __syncthreads();
  for (int off = 1; off < 512; off <<= 1) {
    int u = (t >= off) ? s[t - off] : 0;
    __syncthreads();
    s[t] += u;
    __syncthreads();
  }
  if (t < NBUK) bsum2[t] = s[t] - v;     // exclusive base
  if (t == NBUK - 1) offsets[N] = s[t];  // EP = total padded edges
}

// ---- B2: offsets + scatter pre-shifted byte offsets (self first, pad) -----
__global__ __launch_bounds__(256) void bucket_fill_kernel(
    const int2* __restrict__ edata1, const int* __restrict__ Mscan,
    const int* __restrict__ deg_arr, const int* __restrict__ bsum2, int E,
    int N, int NBUK, int* __restrict__ offsets, int* __restrict__ ed3) {
  __shared__ int scan[256];
  __shared__ int cursor[256];
  const int b = blockIdx.x, t = threadIdx.x;
  const int ebase = Mscan[b * NWGA];
  const int eend = (b + 1 < NBUK) ? Mscan[(b + 1) * NWGA] : E;
  const int nodebase = b << 8;
  const int node = nodebase + t;
  const int dt = (node < N) ? deg_arr[node] : 0;
  const int pd = (dt + 3) & ~3;
  scan[t] = pd;
  __syncthreads();
  for (int off = 1; off < 256; off <<= 1) {
    int u = (t >= off) ? scan[t - off] : 0;
    __syncthreads();
    scan[t] += u;
    __syncthreads();
  }
  const int base = bsum2[b] + scan[t] - pd;
  cursor[t] = base + 1;  // slot 0 = self
  if (node < N) {
    offsets[node] = base;
    ed3[base] = node << 7;  // self edge (byte offset)
    for (int p = dt; p < pd; ++p) ed3[base + p] = N << 7;  // pads -> zero row
  }
  __syncthreads();
  for (int e = ebase + t; e < eend; e += 256) {
    int2 sd = edata1[e];
    int pos = atomicAdd(&cursor[sd.y - nodebase], 1);
    ed3[pos] = sd.x << 7;
  }
}

// ---- zero rows (row N of the two agg input tables) ------------------------
__global__ void zero_rows_kernel(_Float16* a, _Float16* b) {
  if (threadIdx.x < 64) a[threadIdx.x] = (_Float16)0.f;
  else b[threadIdx.x - 64] = (_Float16)0.f;
}

// ---- MFMA GEMM: H[N,D] = X[N,K]@W[K,D] (+bias,relu / *dinv[row]), fp16 out
template <int K, int D, bool BR, bool DSCALE, typename InT>
__global__ __launch_bounds__(256) void gemm_mfma(
    const InT* __restrict__ X, const float* __restrict__ W,
    const float* __restrict__ bias, const float* __restrict__ dinv,
    _Float16* __restrict__ H, int N) {
  __shared__ char lds[2 * K * D];
  const int t = threadIdx.x;
  for (int idx = t; idx < K * D; idx += 256) {
    const int k = idx % K;
    const int d = idx / K;
    const _Float16 v = (_Float16)W[k * D + d];
    const int byte =
        d * (2 * K) + ((((k >> 3) ^ (d & 7)) << 4) | ((k & 7) << 1));
    *(_Float16*)(lds + byte) = v;
  }
  __syncthreads();

  const int w = t >> 6;
  const int l = t & 63;
  const int lrow = l & 15;
  const int lg = l >> 4;
  const int r0 = blockIdx.x * 128 + w * 32;
  if (r0 >= N) return;

  f32x4 acc[2][D / 16];
#pragma unroll
  for (int rt = 0; rt < 2; ++rt)
#pragma unroll
    for (int c = 0; c < D / 16; ++c) acc[rt][c] = (f32x4){0.f, 0.f, 0.f, 0.f};

  int rA[2];
  rA[0] = min(r0 + lrow, N - 1);
  rA[1] = min(r0 + 16 + lrow, N - 1);

#pragma unroll
  for (int s = 0; s < K / 32; ++s) {
    half8 a[2];
#pragma unroll
    for (int rt = 0; rt < 2; ++rt) {
      if constexpr (sizeof(InT) == 2) {
        a[rt] = *reinterpret_cast<const half8*>(
            (const _Float16*)X + (size_t)rA[rt] * K + s * 32 + lg * 8);
      } else {
        const float* xp = (const float*)X + (size_t)rA[rt] * K + s * 32 + lg * 8;
        float4 lo = *reinterpret_cast<const float4*>(xp);
        float4 hi = *reinterpret_cast<const float4*>(xp + 4);
        half8 af;
        af[0] = (_Float16)lo.x; af[1] = (_Float16)lo.y;
        af[2] = (_Float16)lo.z; af[3] = (_Float16)lo.w;
        af[4] = (_Float16)hi.x; af[5] = (_Float16)hi.y;
        af[6] = (_Float16)hi.z; af[7] = (_Float16)hi.w;
        a[rt] = af;
      }
    }
    half8 b[D / 16];
#pragma unroll
    for (int c = 0; c < D / 16; ++c) {
      const int d = c * 16 + lrow;
      const int g = s * 4 + lg;
      b[c] = *reinterpret_cast<const half8*>(
          lds + d * (2 * K) + (((g ^ (d & 7)) << 4)));
    }
#pragma unroll
    for (int rt = 0; rt < 2; ++rt)
#pragma unroll
      for (int c = 0; c < D / 16; ++c)
        acc[rt][c] = __builtin_amdgcn_mfma_f32_16x16x32_f16(a[rt], b[c],
                                                            acc[rt][c], 0, 0, 0);
  }

  float bv[D / 16];
  if (BR) {
#pragma unroll
    for (int c = 0; c < D / 16; ++c) bv[c] = bias[c * 16 + lrow];
  }
#pragma unroll
  for (int rt = 0; rt < 2; ++rt) {
#pragma unroll
    for (int r = 0; r < 4; ++r) {
      const int row = r0 + rt * 16 + lg * 4 + r;
      if (row < N) {
        float ds = 1.f;
        if (DSCALE) ds = dinv[row];
#pragma unroll
        for (int c = 0; c < D / 16; ++c) {
          float v = acc[rt][c][r];
          if (BR) v = fmaxf(v + bv[c], 0.f);
          if (DSCALE) v *= ds;
          H[(size_t)row * D + c * 16 + lrow] = (_Float16)v;
        }
      }
    }
  }
}

// ---- Aggregation: wave = 8 nodes, quad-gather (4 edges / wave-load) -------
template <bool BIAS, bool RELU, bool SCALE_OUT, typename OutT>
__global__ __launch_bounds__(256) void agg_kernel(
    const __half* __restrict__ h, const int* __restrict__ ed,
    const int* __restrict__ offsets, const float* __restrict__ dinv,
    const float* __restrict__ bias, OutT* __restrict__ out, int N) {
  const int wid = blockIdx.x * 4 + (threadIdx.x >> 6);
  const int na = wid * 8;
  if (na >= N) return;
  const int lane = threadIdx.x & 63;
  const int grp = lane >> 4;  // quad slot: edge (j + grp)
  const int fq = lane & 15;   // feature quad: features 4fq..4fq+3
  const int nrem = min(8, N - na);

  const int off_l = offsets[na + min(lane, nrem)];
  const float dn_l = dinv[na + min(lane, nrem - 1)];
  const int eb0 = __shfl(off_l, 0);
  const int eb1 = __shfl(off_l, nrem);
  float4 bsv = make_float4(0.f, 0.f, 0.f, 0.f);
  if (BIAS) bsv = *reinterpret_cast<const float4*>(&bias[fq * 4]);

  // pre-issue ALL edge-offset loads, lane-spread (coalesced 256B each)
  int pe[CMAX];
#pragma unroll
  for (int c = 0; c < CMAX; ++c) {
    int idx = eb0 + c * 64 + lane;
    pe[c] = ed[min(idx, eb1 - 1)];
  }

  const char* hb = (const char*)h + (fq << 3);
  float4 acc = make_float4(0.f, 0.f, 0.f, 0.f);
  int cur = 0;
  int bnd = __shfl(off_l, 1);
  float dn = __shfl(dn_l, 0);
  int j = eb0;

  auto flush = [&]() {
    float sx = acc.x, sy = acc.y, sz = acc.z, sw = acc.w;
    sx += __shfl_xor(sx, 16); sx += __shfl_xor(sx, 32);
    sy += __shfl_xor(sy, 16); sy += __shfl_xor(sy, 32);
    sz += __shfl_xor(sz, 16); sz += __shfl_xor(sz, 32);
    sw += __shfl_xor(sw, 16); sw += __shfl_xor(sw, 32);
    float vx = sx * dn, vy = sy * dn, vz = sz * dn, vw = sw * dn;
    if (BIAS) { vx += bsv.x; vy += bsv.y; vz += bsv.z; vw += bsv.w; }
    if (RELU) {
      vx = fmaxf(vx, 0.f); vy = fmaxf(vy, 0.f);
      vz = fmaxf(vz, 0.f); vw = fmaxf(vw, 0.f);
    }
    if (SCALE_OUT) { vx *= dn; vy *= dn; vz *= dn; vw *= dn; }
    if (lane < 16) {
      if constexpr (sizeof(OutT) == 2) {
        __half2 h0 = __floats2half2_rn(vx, vy);
        __half2 h1 = __floats2half2_rn(vz, vw);
        uint2 pk = make_uint2(*(unsigned int*)&h0, *(unsigned int*)&h1);
        *reinterpret_cast<uint2*>((char*)out + ((size_t)(na + cur) << 7) +
                                  (fq << 3)) = pk;
      } else {
        *reinterpret_cast<float4*>((char*)out + ((size_t)(na + cur) << 8) +
                                   (fq << 4)) = make_float4(vx, vy, vz, vw);
      }
    }
    acc = make_float4(0.f, 0.f, 0.f, 0.f);
    cur++;
    bnd = __shfl(off_l, min(cur + 1, 8));
    dn = __shfl(dn_l, min(cur, 7));
  };

#pragma unroll
  for (int c = 0; c < CMAX; ++c) {
    if (j < eb1) {
      const int pc = pe[c];  // static index
      for (int kb = 0; kb < 64; kb += 16) {  // 4 quads = 16 edges per iter
        if (j >= eb1) break;
        int so[4];
        uint2 gq[4];
#pragma unroll
        for (int q = 0; q < 4; ++q) so[q] = __shfl(pc, kb + 4 * q + grp);
#pragma unroll
        for (int q = 0; q < 4; ++q)
          gq[q] = *reinterpret_cast<const uint2*>(hb + (size_t)(unsigned)so[q]);
#pragma unroll
        for (int q = 0; q < 4; ++q) {
          if (j == bnd) flush();
          float2 lo = __half22float2(*reinterpret_cast<__half2*>(&gq[q].x));
          float2 hi = __half22float2(*reinterpret_cast<__half2*>(&gq[q].y));
          acc.x += lo.x; acc.y += lo.y; acc.z += hi.x; acc.w += hi.y;
          j += 4;
        }
      }
    }
  }
  // fallback for runs > CMAX*64 edges (quad mode, direct loads)
  for (; j < eb1; j += 4) {
    int so = ed[j + grp];
    uint2 g = *reinterpret_cast<const uint2*>(hb + (size_t)(unsigned)so);
    if (j == bnd) flush();
    float2 lo = __half22float2(*reinterpret_cast<__half2*>(&g.x));
    float2 hi = __half22float2(*reinterpret_cast<__half2*>(&g.y));
    acc.x += lo.x; acc.y += lo.y; acc.z += hi.x; acc.w += hi.y;
  }
  if (cur < nrem) flush();
}

extern "C" void kernel_launch(void* const* d_in, const int* in_sizes, int n_in,
                              void* d_out, int out_size, void* d_ws,
                              size_t ws_size, hipStream_t stream) {
  const float* x  = (const float*)d_in[0];
  const int*   ei = (const int*)d_in[1];
  const float* W1 = (const float*)d_in[2];
  const float* b1 = (const float*)d_in[3];
  const float* W2 = (const float*)d_in[4];
  const float* b2 = (const float*)d_in[5];
  const float* W3 = (const float*)d_in[6];
  const float* b3 = (const float*)d_in[7];

  const int N = in_sizes[0] / 128;
  const int E = in_sizes[1] / 2;
  const int NBUK = (N + 255) >> 8;          // 391 for N=100000
  const int MLEN = NBUK * NWGA;             // 100096
  const int chunk = (E + NWGA - 1) / NWGA;  // 6250

  // Workspace (~62 MB) with lifetime aliasing:
  //  perm   : offsets, dinv, deg, bsum2, edata3 (padded, <= E+4N)
  //  regionA: {M, bsum}(build)   -> ht1 ((N+1) x 64 fp16; row N = zeros)
  //  regionB: edata1(build)      -> a2  (N x 64 fp16)
  //  regionC: hout1 ((N+1) rows) -> h2  (N x 128 fp16)
  char* w = (char*)d_ws;
  int* offsets = (int*)w;      w += (size_t)(N + 2) * 4;
  float* dinv = (float*)w;     w += (size_t)N * 4;
  int* deg_arr = (int*)w;      w += (size_t)N * 4;
  int* bsum2 = (int*)w;        w += 512 * 4;
  w = (char*)(((uintptr_t)w + 255) & ~(uintptr_t)255);
  int* edata3 = (int*)w;       w += (size_t)(E + 4 * N + 64) * 4;
  w = (char*)(((uintptr_t)w + 255) & ~(uintptr_t)255);
  char* regionA = w;           w += (size_t)(N + 1) * 64 * 2;
  w = (char*)(((uintptr_t)w + 255) & ~(uintptr_t)255);
  char* regionB = w;           w += (size_t)E * 8;
  w = (char*)(((uintptr_t)w + 255) & ~(uintptr_t)255);
  char* regionC = w;           w += (size_t)N * 128 * 2;

  int* M = (int*)regionA;                 // 0.4 MB (below ht1 row N)
  int* bsum = M + MLEN;                   // 2 KB
  _Float16* ht1 = (_Float16*)regionA;     // gemm1/3 out, agg1/3 in
  int2* edata1 = (int2*)regionB;          // E*8 = 12.8 MB
  _Float16* a2 = (_Float16*)regionB;      // after build, N*64*2
  _Float16* hout1 = (_Float16*)regionC;   // agg1 -> agg2 ((N+1) rows)
  _Float16* h2 = (_Float16*)regionC;      // gemm2 -> gemm3, N*128*2

  const int NBS = (MLEN + 255) / 256;  // 391 (<=512)
  const int NW = (N + 7) / 8;          // aggregation waves
  const int AGB = (NW + 3) / 4;        // aggregation blocks
  const int GGB = (N + 127) / 128;     // gemm blocks

  // ---- CSR build (self-loops + pad-to-4; pre-shifted edge stream) ----
  zero_rows_kernel<<<1, 128, 0, stream>>>(ht1 + (size_t)N * 64,
                                          hout1 + (size_t)N * 64);
  bucket_hist_kernel<<<NWGA, 256, 0, stream>>>(ei + E, E, chunk, NBUK, M);
  scan_blocksum<<<NBS, 256, 0, stream>>>(M, MLEN, bsum);
  scan_bsums<<<1, 512, 0, stream>>>(bsum, NBS);
  scan_final<<<NBS, 256, 0, stream>>>(M, MLEN, bsum);
  bucket_scatter_kernel<<<NWGA, 256, 0, stream>>>(ei, E, chunk, NBUK, M, edata1);
  bucket_deg_kernel<<<NBUK, 256, 0, stream>>>(edata1, M, E, N, NBUK, deg_arr,
                                              dinv, bsum2);
  bucket_base_scan<<<1, 512, 0, stream>>>(bsum2, NBUK, offsets, N);
  bucket_fill_kernel<<<NBUK, 256, 0, stream>>>(edata1, M, deg_arr, bsum2, E, N,
                                               NBUK, offsets, edata3);

  // ---- Layer 1 ----
  gemm_mfma<128, 64, false, true, float><<<GGB, 256, 0, stream>>>(
      x, W1, nullptr, dinv, ht1, N);
  agg_kernel<true, true, true, __half><<<AGB, 256, 0, stream>>>(
      (const __half*)ht1, edata3, offsets, dinv, b1, (__half*)hout1, N);

  // ---- Layer 2 ----
  agg_kernel<false, false, false, __half><<<AGB, 256, 0, stream>>>(
      (const __half*)hout1, edata3, offsets, dinv, nullptr, (__half*)a2, N);
  gemm_mfma<64, 128, true, false, _Float16><<<GGB, 256, 0, stream>>>(
      a2, W2, b2, nullptr, h2, N);

  // ---- Layer 3 ----
  gemm_mfma<128, 64, false, true, _Float16><<<GGB, 256, 0, stream>>>(
      h2, W3, nullptr, dinv, ht1, N);
  agg_kernel<true, false, false, float><<<AGB, 256, 0, stream>>>(
      (const __half*)ht1, edata3, offsets, dinv, b3, (float*)d_out, N);
}